// Round 8
// baseline (1486.225 us; speedup 1.0000x reference)
//
#include <hip/hip_runtime.h>

#define TT 512
#define BB 16
#define DD 256
#define HHH 128
#define GG 32
#define ZZ 8
#define RR_ 16
#define NAA 18

typedef _Float16 h2v __attribute__((ext_vector_type(2)));

__device__ __forceinline__ float sigmoid_(float x) { return 1.f / (1.f + __expf(-x)); }
__device__ __forceinline__ float tanh_(float x) { float e = __expf(2.f * x); return 1.f - 2.f / (e + 1.f); }
__device__ __forceinline__ float dot4(float4 a, float4 b) {
    return a.x * b.x + a.y * b.y + a.z * b.z + a.w * b.w;
}
__device__ __forceinline__ h2v u2h2(unsigned u) { union { unsigned u; h2v h; } c; c.u = u; return c.h; }

// park a dword in an AGPR / fetch it back (opaque to the register allocator)
#define AGPR_STORE(a, v) asm volatile("v_accvgpr_write_b32 %0, %1" : "=a"(a) : "v"(v))
#define AGPR_LOAD(v, a)  asm volatile("v_accvgpr_read_b32 %0, %1" : "=v"(v) : "a"(a))

// ---------------------------------------------------------------------------
// Pack recurrent weights to f16 pairs.
// gru pk  (49152 dw): i -> (dir, s, k, j, m): half2(Wd[j*128+k][32s+2m], +1)
// ctrl pk_e (1536 dw): i -> (s, k, j, m):     half2(We[j*32+k][8s+2m], +1)
// ---------------------------------------------------------------------------
__global__ __launch_bounds__(256) void pack_w(
    const float* __restrict__ wf, const float* __restrict__ wb,
    const float* __restrict__ we,
    unsigned* __restrict__ pk, unsigned* __restrict__ pk_e)
{
    int i = blockIdx.x * 256 + threadIdx.x;          // 0 .. 50687
    if (i < 49152) {
        int dir = i / 24576; int r = i % 24576;
        int s = r / 6144;    int rem = r % 6144;
        int k = rem / 48;    int e = rem % 48;
        int j = e / 16;      int m = e % 16;
        const float* w = dir ? wb : wf;
        int row = j * 128 + k, k0 = 32 * s + 2 * m;
        union { _Float16 h[2]; unsigned u; } c;
        c.h[0] = (_Float16)w[row * 128 + k0];
        c.h[1] = (_Float16)w[row * 128 + k0 + 1];
        pk[i] = c.u;
    } else if (i < 50688) {
        int ie = i - 49152;
        int s = ie / 384;  int rem = ie % 384;
        int k = rem / 12;  int e = rem % 12;
        int j = e / 4;     int m = e % 4;
        int row = j * 32 + k, k0 = 8 * s + 2 * m;
        union { _Float16 h[2]; unsigned u; } c;
        c.h[0] = (_Float16)we[row * 32 + k0];
        c.h[1] = (_Float16)we[row * 32 + k0 + 1];
        pk_e[ie] = c.u;
    }
}

// ---------------------------------------------------------------------------
// Generic tiled GEMM: Out[p][n] (+)= bias[n] + sum_k A[p*K+k] * W[n*ldw+k]
// float4 LDS inner loop (pad 36 keeps 16B alignment; 2-way banks are free).
// ---------------------------------------------------------------------------
__global__ __launch_bounds__(256) void gemm_k(
    const float* __restrict__ A, int K, const float* __restrict__ W, int ldw,
    const float* __restrict__ bias, float* __restrict__ Out, int ldout, int N, int accFlag)
{
    __shared__ float At[64][36];
    __shared__ float Wt[32][36];
    int row0 = blockIdx.x * 64, n0 = blockIdx.y * 32;
    int tid = threadIdx.x;
    int tx = tid & 15, ty = tid >> 4;
    float acc[4][2] = {};
    for (int k0 = 0; k0 < K; k0 += 32) {
        #pragma unroll
        for (int i = 0; i < 8; ++i) {
            int idx = tid + i * 256; int rr = idx >> 5, kk = idx & 31;
            At[rr][kk] = A[(size_t)(row0 + rr) * K + k0 + kk];
        }
        #pragma unroll
        for (int i = 0; i < 4; ++i) {
            int idx = tid + i * 256; int nn = idx >> 5, kk = idx & 31;
            Wt[nn][kk] = (n0 + nn < N) ? W[(size_t)(n0 + nn) * ldw + k0 + kk] : 0.f;
        }
        __syncthreads();
        #pragma unroll
        for (int kk = 0; kk < 32; kk += 4) {
            float4 w0 = *(const float4*)&Wt[tx][kk];
            float4 w1 = *(const float4*)&Wt[tx + 16][kk];
            #pragma unroll
            for (int rr = 0; rr < 4; ++rr) {
                float4 av = *(const float4*)&At[ty * 4 + rr][kk];
                acc[rr][0] += dot4(av, w0);
                acc[rr][1] += dot4(av, w1);
            }
        }
        __syncthreads();
    }
    #pragma unroll
    for (int cc = 0; cc < 2; ++cc) {
        int n = n0 + tx + cc * 16;
        if (n < N) {
            float badd = bias ? bias[n] : 0.f;
            #pragma unroll
            for (int rr = 0; rr < 4; ++rr) {
                int row = row0 + ty * 4 + rr;
                float v = acc[rr][cc] + badd;
                if (accFlag) Out[(size_t)row * ldout + n] += v;
                else         Out[(size_t)row * ldout + n] = v;
            }
        }
    }
}

// ---------------------------------------------------------------------------
// Bidirectional GRU recurrence. 32 WGs = (dir,b). 512 threads (8 waves).
// tid = k*4 + s: the 4 k-slice partials of hidden unit k live in 4 adjacent
// lanes of ONE wave -> reduced with 2x shfl_xor. All three gate rows
// (k,128+k,256+k) land in lane s=0 -> gates in-lane, NO LDS partial
// exchange, ONE barrier/step. h double-buffered f16 in LDS. Weights f16
// in AGPRs (R7). R2..R7 all ~360-426us were critical-path-bound on the
// 2-barrier + LDS-part skeleton; this removes it.
// ---------------------------------------------------------------------------
__global__ __launch_bounds__(512, 2) void gru_seq(
    const float* __restrict__ gi_f, const float* __restrict__ gi_b,
    const unsigned* __restrict__ pk,
    const float* __restrict__ bhh_f, const float* __restrict__ bhh_b,
    float* __restrict__ s_seq)
{
    int bx = blockIdx.x;
    int dir = bx >> 4, b = bx & 15;
    const float* gi  = dir ? gi_b  : gi_f;
    const float* bhh = dir ? bhh_b : bhh_f;
    int tid = threadIdx.x;
    int k = tid >> 2;            // hidden unit 0..127
    int s = tid & 3;             // k-slice 0..3 (32 k-values each)

    // one-time: this thread's 48 weight dwords (rows k,128+k,256+k; slice s)
    unsigned ag[48];
    {
        const uint4* wp = (const uint4*)(pk + ((size_t)(dir * 4 + s) * 128 + k) * 48);
        #pragma unroll
        for (int i = 0; i < 12; ++i) {
            uint4 u = wp[i];
            AGPR_STORE(ag[4 * i + 0], u.x);
            AGPR_STORE(ag[4 * i + 1], u.y);
            AGPR_STORE(ag[4 * i + 2], u.z);
            AGPR_STORE(ag[4 * i + 3], u.w);
        }
    }

    __shared__ __align__(16) _Float16 hbuf[2][128];
    if (tid < 128) hbuf[0][tid] = (_Float16)0.f;

    float bhr = 0.f, bhz = 0.f, bhn = 0.f;
    float gra = 0.f, gza = 0.f, gna = 0.f;
    float grb = 0.f, gzb = 0.f, gnb = 0.f;
    float hreg = 0.f;
    if (s == 0) {
        bhr = bhh[k]; bhz = bhh[128 + k]; bhn = bhh[256 + k];
        int t0 = dir ? 511 : 0;
        int t1 = dir ? 510 : 1;
        size_t p0 = (size_t)(b * TT + t0) * 384;
        size_t p1 = (size_t)(b * TT + t1) * 384;
        gra = gi[p0 + k]; gza = gi[p0 + 128 + k]; gna = gi[p0 + 256 + k];
        grb = gi[p1 + k]; gzb = gi[p1 + 128 + k]; gnb = gi[p1 + 256 + k];
    }
    __syncthreads();

    int cur = 0;
    auto body = [&](int step, float& gr, float& gz, float& gn) {
        // h slice s: 32 f16 = 4 uint4 from LDS
        const uint4* hv = (const uint4*)(&hbuf[cur][0]) + s * 4;
        uint4 hA = hv[0], hB = hv[1], hC = hv[2], hD = hv[3];
        unsigned hw[16] = { hA.x, hA.y, hA.z, hA.w, hB.x, hB.y, hB.z, hB.w,
                            hC.x, hC.y, hC.z, hC.w, hD.x, hD.y, hD.z, hD.w };
        float a0 = 0.f, a1 = 0.f, a2 = 0.f;
        #pragma unroll
        for (int m = 0; m < 16; ++m) {
            unsigned w0, w1, w2;
            AGPR_LOAD(w0, ag[m]);
            AGPR_LOAD(w1, ag[16 + m]);
            AGPR_LOAD(w2, ag[32 + m]);
            h2v hh = u2h2(hw[m]);
            a0 = __builtin_amdgcn_fdot2(u2h2(w0), hh, a0, false);
            a1 = __builtin_amdgcn_fdot2(u2h2(w1), hh, a1, false);
            a2 = __builtin_amdgcn_fdot2(u2h2(w2), hh, a2, false);
        }
        // reduce the 4 slice-partials (lanes k*4 .. k*4+3, same wave)
        a0 += __shfl_xor(a0, 1); a0 += __shfl_xor(a0, 2);
        a1 += __shfl_xor(a1, 1); a1 += __shfl_xor(a1, 2);
        a2 += __shfl_xor(a2, 1); a2 += __shfl_xor(a2, 2);

        if (s == 0) {
            int t = dir ? (511 - step) : step;
            int p = b * TT + t;
            float r = sigmoid_(gr + bhr + a0);
            float z = sigmoid_(gz + bhz + a1);
            float n = tanh_(gn + r * (bhn + a2));
            float hn = (1.f - z) * n + z * hreg;
            hreg = hn;
            hbuf[cur ^ 1][k] = (_Float16)hn;
            s_seq[(size_t)p * 256 + dir * 128 + k] = hn;
            int s2 = step + 2;
            int tp = (s2 < 512) ? (dir ? (511 - s2) : s2) : t;
            size_t p2 = (size_t)(b * TT + tp) * 384;
            gr = gi[p2 + k]; gz = gi[p2 + 128 + k]; gn = gi[p2 + 256 + k];
        }
        __syncthreads();
        cur ^= 1;
    };

    for (int step = 0; step < 512; step += 2) {
        body(step,     gra, gza, gna);
        body(step + 1, grb, gzb, gnb);
    }
}

// ---------------------------------------------------------------------------
// Controller h-scan. 16 WGs, 128 threads (2 waves). Same single-barrier
// shfl-reduce structure as gru_seq: tid = k*4 + s, k<32, s = 8-wide slice.
// ---------------------------------------------------------------------------
__global__ __launch_bounds__(128, 1) void ctrl_h_scan(
    const float* __restrict__ gie, const unsigned* __restrict__ pk_e,
    const float* __restrict__ bhh_e, float* __restrict__ h_seq)
{
    int b = blockIdx.x, tid = threadIdx.x;
    int k = tid >> 2;            // hidden unit 0..31
    int s = tid & 3;             // slice 0..3 (8 h-values each)

    unsigned ag[12];
    {
        const uint4* wp = (const uint4*)(pk_e + ((size_t)(s * 32) + k) * 12);
        #pragma unroll
        for (int i = 0; i < 3; ++i) {
            uint4 u = wp[i];
            AGPR_STORE(ag[4 * i + 0], u.x);
            AGPR_STORE(ag[4 * i + 1], u.y);
            AGPR_STORE(ag[4 * i + 2], u.z);
            AGPR_STORE(ag[4 * i + 3], u.w);
        }
    }

    __shared__ __align__(16) _Float16 hb[2][32];
    if (tid < 32) hb[0][tid] = (_Float16)0.f;

    int pbase = b * TT;
    float bhr = 0.f, bhz = 0.f, bhn = 0.f;
    float g1a = 0.f, g2a = 0.f, g3a = 0.f, g1b = 0.f, g2b = 0.f, g3b = 0.f;
    float hreg = 0.f;
    if (s == 0) {
        bhr = bhh_e[k]; bhz = bhh_e[32 + k]; bhn = bhh_e[64 + k];
        size_t p0 = (size_t)pbase * 96, p1 = (size_t)(pbase + 1) * 96;
        g1a = gie[p0 + k]; g2a = gie[p0 + 32 + k]; g3a = gie[p0 + 64 + k];
        g1b = gie[p1 + k]; g2b = gie[p1 + 32 + k]; g3b = gie[p1 + 64 + k];
    }
    __syncthreads();

    int cur = 0;
    auto body = [&](int t, float& g1, float& g2, float& g3) {
        const uint4* hv = (const uint4*)(&hb[cur][0]) + s;
        uint4 h4 = hv[0];
        unsigned hw[4] = { h4.x, h4.y, h4.z, h4.w };
        float a0 = 0.f, a1 = 0.f, a2 = 0.f;
        #pragma unroll
        for (int m = 0; m < 4; ++m) {
            unsigned w0, w1, w2;
            AGPR_LOAD(w0, ag[m]);
            AGPR_LOAD(w1, ag[4 + m]);
            AGPR_LOAD(w2, ag[8 + m]);
            h2v hh = u2h2(hw[m]);
            a0 = __builtin_amdgcn_fdot2(u2h2(w0), hh, a0, false);
            a1 = __builtin_amdgcn_fdot2(u2h2(w1), hh, a1, false);
            a2 = __builtin_amdgcn_fdot2(u2h2(w2), hh, a2, false);
        }
        a0 += __shfl_xor(a0, 1); a0 += __shfl_xor(a0, 2);
        a1 += __shfl_xor(a1, 1); a1 += __shfl_xor(a1, 2);
        a2 += __shfl_xor(a2, 1); a2 += __shfl_xor(a2, 2);

        if (s == 0) {
            float r = sigmoid_(g1 + bhr + a0);
            float z = sigmoid_(g2 + bhz + a1);
            float n = tanh_(g3 + r * (bhn + a2));
            float hn = (1.f - z) * n + z * hreg;
            hreg = hn;
            hb[cur ^ 1][k] = (_Float16)hn;
            h_seq[(size_t)(pbase + t) * 32 + k] = hn;
            int t2 = (t + 2 < 512) ? t + 2 : t;
            size_t p2 = (size_t)(pbase + t2) * 96;
            g1 = gie[p2 + k]; g2 = gie[p2 + 32 + k]; g3 = gie[p2 + 64 + k];
        }
        __syncthreads();
        cur ^= 1;
    };

    for (int t = 0; t < 512; t += 2) {
        body(t,     g1a, g2a, g3a);
        body(t + 1, g1b, g2b, g3b);
    }
}

// ---------------------------------------------------------------------------
// Controller z/beta scan. 16 WGs, 1 wave, no LDS, no barriers.
// ---------------------------------------------------------------------------
__global__ __launch_bounds__(64, 1) void ctrl_z_scan(
    const float* __restrict__ hid_pre, const float* __restrict__ sw1_w,
    const float* __restrict__ sw2_w, const float* __restrict__ sw2_b,
    const float* __restrict__ eps, const float* __restrict__ mu_o,
    const float* __restrict__ lv_o, float* __restrict__ beta_o, float* __restrict__ z_o)
{
    int b = blockIdx.x, q = threadIdx.x;
    float wz[8];
    #pragma unroll
    for (int x = 0; x < 8; ++x) wz[x] = sw1_w[(size_t)q * 296 + 288 + x];
    float w2 = sw2_w[q];
    float bb = sw2_b[0];
    float zc = 0.f;
    int pbase = b * TT;

    float hpa = hid_pre[(size_t)pbase * 64 + q];
    float hpb = hid_pre[(size_t)(pbase + 1) * 64 + q];
    float mua = 0.f, lva = 0.f, epa = 0.f, mub = 0.f, lvb = 0.f, epb = 0.f;
    if (q < 8) {
        mua = mu_o[pbase * 8 + q]; lva = lv_o[pbase * 8 + q]; epa = eps[pbase * 8 + q];
        mub = mu_o[(pbase + 1) * 8 + q]; lvb = lv_o[(pbase + 1) * 8 + q]; epb = eps[(pbase + 1) * 8 + q];
    }

    auto body = [&](int t, float& hp, float& mu, float& lv, float& ep) {
        int p = pbase + t;
        float a = hp;
        #pragma unroll
        for (int x = 0; x < 8; ++x) a += wz[x] * __shfl(zc, x);
        float hid = tanh_(a);
        float prod = w2 * hid;
        #pragma unroll
        for (int m = 32; m >= 1; m >>= 1) prod += __shfl_xor(prod, m);
        float beta = sigmoid_(prod + bb);
        float zn = beta * (mu + __expf(0.5f * lv) * ep) + (1.f - beta) * zc;
        zc = zn;                      // meaningful in lanes 0-7 only
        if (q < 8) z_o[p * 8 + q] = zn;
        if (q == 0) beta_o[p] = beta;
        int t2 = (t + 2 < 512) ? t + 2 : t;
        hp = hid_pre[(size_t)(pbase + t2) * 64 + q];
        if (q < 8) {
            mu = mu_o[(pbase + t2) * 8 + q];
            lv = lv_o[(pbase + t2) * 8 + q];
            ep = eps[(pbase + t2) * 8 + q];
        }
    };

    for (int t = 0; t < 512; t += 2) {
        body(t,     hpa, mua, lva, epa);
        body(t + 1, hpb, mub, lvb, epb);
    }
}

// ---------------------------------------------------------------------------
// Decoder hypernet + rank-R perturbation + LayerNorm + head. P=8/WG.
// ---------------------------------------------------------------------------
__global__ __launch_bounds__(256, 3) void decoder_final(
    const float* __restrict__ e_seq, const float* __restrict__ z_o,
    const float* __restrict__ dec1_w, const float* __restrict__ dec1_b,
    const float* __restrict__ dec2_w, const float* __restrict__ dec2_b,
    const float* __restrict__ ln_g, const float* __restrict__ ln_b,
    const float* __restrict__ head_w, const float* __restrict__ head_b,
    float* __restrict__ logits)
{
    __shared__ __align__(16) float e_l[8][256];
    __shared__ __align__(16) float hmid[8][32];
    __shared__ float zl[8][8];
    __shared__ float tmpw[8][16];
    __shared__ __align__(16) float partb[2048];
    __shared__ float red1[8][16];
    __shared__ float red2[8][16];
    __shared__ float stats[8][2];
    int tid = threadIdx.x;
    int p0 = blockIdx.x * 8;

    {
        const float4* eg = (const float4*)(e_seq + (size_t)p0 * 256);
        float4* el4 = (float4*)&e_l[0][0];
        el4[tid] = eg[tid];
        el4[tid + 256] = eg[tid + 256];
        if (tid < 64) ((float*)zl)[tid] = z_o[p0 * 8 + tid];
    }
    __syncthreads();
    {
        int pp = tid >> 5, g = tid & 31;
        float a = dec1_b[g];
        #pragma unroll
        for (int x = 0; x < 8; ++x) a += dec1_w[g * 8 + x] * zl[pp][x];
        hmid[pp][g] = tanh_(a);
    }
    __syncthreads();
    // ---- pass B: tmp[pp][r] = sum_d Bm[d,r]*e[d]
    {
        int r = tid & 15, dgrp = tid >> 4;
        float acc[8];
        #pragma unroll
        for (int pp = 0; pp < 8; ++pp) acc[pp] = 0.f;
        for (int iblk = 0; iblk < 8; ++iblk) {
            float4 wr[2][8]; float wb[2]; int dd[2];
            #pragma unroll
            for (int ii = 0; ii < 2; ++ii) {
                int d = dgrp + 16 * (iblk * 2 + ii);
                dd[ii] = d;
                int row = 4096 + d * 16 + r;
                const float4* wp = (const float4*)(dec2_w + (size_t)row * 32);
                #pragma unroll
                for (int g = 0; g < 8; ++g) wr[ii][g] = wp[g];
                wb[ii] = dec2_b[row];
            }
            #pragma unroll 1
            for (int pp = 0; pp < 8; ++pp) {
                const float4* hv = (const float4*)hmid[pp];
                float b0 = wb[0], b1 = wb[1];
                #pragma unroll
                for (int g = 0; g < 8; ++g) {
                    float4 hh = hv[g];
                    b0 += dot4(wr[0][g], hh);
                    b1 += dot4(wr[1][g], hh);
                }
                acc[pp] += b0 * e_l[pp][dd[0]] + b1 * e_l[pp][dd[1]];
            }
        }
        #pragma unroll
        for (int pp = 0; pp < 8; ++pp) partb[(pp * 16 + r) * 16 + dgrp] = acc[pp];
    }
    __syncthreads();
    if (tid < 128) {
        int pp = tid >> 4, rr = tid & 15;
        float s = 0.f;
        #pragma unroll
        for (int dg = 0; dg < 16; ++dg) s += partb[(pp * 16 + rr) * 16 + dg];
        tmpw[pp][rr] = s;
    }
    __syncthreads();
    // ---- pass A
    {
        int d = tid;
        float po[8];
        #pragma unroll
        for (int pp = 0; pp < 8; ++pp) po[pp] = e_l[pp][d];
        for (int rblk = 0; rblk < 8; ++rblk) {
            float4 wr[2][8]; float wb[2];
            #pragma unroll
            for (int ii = 0; ii < 2; ++ii) {
                int row = d * 16 + rblk * 2 + ii;
                const float4* wp = (const float4*)(dec2_w + (size_t)row * 32);
                #pragma unroll
                for (int g = 0; g < 8; ++g) wr[ii][g] = wp[g];
                wb[ii] = dec2_b[row];
            }
            #pragma unroll 1
            for (int pp = 0; pp < 8; ++pp) {
                const float4* hv = (const float4*)hmid[pp];
                float a0 = wb[0], a1 = wb[1];
                #pragma unroll
                for (int g = 0; g < 8; ++g) {
                    float4 hh = hv[g];
                    a0 += dot4(wr[0][g], hh);
                    a1 += dot4(wr[1][g], hh);
                }
                po[pp] += a0 * tmpw[pp][rblk * 2] + a1 * tmpw[pp][rblk * 2 + 1];
            }
        }
        #pragma unroll
        for (int pp = 0; pp < 8; ++pp) partb[pp * 256 + d] = po[pp];
    }
    __syncthreads();
    if (tid < 128) {
        int pp = tid >> 4, c = tid & 15;
        float s = 0.f, s2 = 0.f;
        #pragma unroll
        for (int i = 0; i < 16; ++i) { float v = partb[pp * 256 + c * 16 + i]; s += v; s2 += v * v; }
        red1[pp][c] = s; red2[pp][c] = s2;
    }
    __syncthreads();
    if (tid < 8) {
        float s = 0.f, s2 = 0.f;
        #pragma unroll
        for (int c = 0; c < 16; ++c) { s += red1[tid][c]; s2 += red2[tid][c]; }
        float mean = s * (1.f / 256.f);
        float var = s2 * (1.f / 256.f) - mean * mean;
        stats[tid][0] = mean;
        stats[tid][1] = rsqrtf(var + 1e-5f);
    }
    __syncthreads();
    {
        int d = tid;
        float g = ln_g[d], bln = ln_b[d];
        #pragma unroll
        for (int pp = 0; pp < 8; ++pp) {
            float v = (partb[pp * 256 + d] - stats[pp][0]) * stats[pp][1];
            partb[pp * 256 + d] = v * g + bln;
        }
    }
    __syncthreads();
    if (tid < 144) {
        int pp = tid / 18, na = tid - pp * 18;
        float a = head_b[na];
        for (int d2 = 0; d2 < 256; ++d2)
            a += partb[pp * 256 + d2] * head_w[na * 256 + d2];
        logits[(size_t)(p0 + pp) * 18 + na] = a;
    }
}

// ---------------------------------------------------------------------------
extern "C" void kernel_launch(void* const* d_in, const int* in_sizes, int n_in,
                              void* d_out, int out_size, void* d_ws, size_t ws_size,
                              hipStream_t stream) {
    (void)in_sizes; (void)n_in; (void)out_size; (void)ws_size;
    const float* e     = (const float*)d_in[0];
    const float* eps   = (const float*)d_in[1];
    const float* wih_f = (const float*)d_in[2];
    const float* whh_f = (const float*)d_in[3];
    const float* bih_f = (const float*)d_in[4];
    const float* bhh_f = (const float*)d_in[5];
    const float* wih_b = (const float*)d_in[6];
    const float* whh_b = (const float*)d_in[7];
    const float* bih_b = (const float*)d_in[8];
    const float* bhh_b = (const float*)d_in[9];
    const float* wih_e = (const float*)d_in[10];
    const float* whh_e = (const float*)d_in[11];
    const float* bih_e = (const float*)d_in[12];
    const float* bhh_e = (const float*)d_in[13];
    const float* mu_w  = (const float*)d_in[14];
    const float* mu_b  = (const float*)d_in[15];
    const float* lv_w  = (const float*)d_in[16];
    const float* lv_b  = (const float*)d_in[17];
    const float* sw1_w = (const float*)d_in[18];
    const float* sw1_b = (const float*)d_in[19];
    const float* sw2_w = (const float*)d_in[20];
    const float* sw2_b = (const float*)d_in[21];
    const float* dec1_w = (const float*)d_in[22];
    const float* dec1_b = (const float*)d_in[23];
    const float* dec2_w = (const float*)d_in[24];
    const float* dec2_b = (const float*)d_in[25];
    const float* ln_g  = (const float*)d_in[26];
    const float* ln_b  = (const float*)d_in[27];
    const float* head_w = (const float*)d_in[28];
    const float* head_b = (const float*)d_in[29];

    float* ws    = (float*)d_ws;
    float* gi_f  = ws;                       // 8192*384
    float* gi_b  = gi_f + 3145728;           // 8192*384
    float* gie   = gi_b + 3145728;           // 8192*96
    float* swe   = gie + 786432;             // 8192*64 (hid_pre)
    float* s_seq = swe + 524288;             // 8192*256
    float* h_seq = s_seq + 2097152;          // 8192*32
    unsigned* pk   = (unsigned*)(h_seq + 262144);  // 49152 dwords (gru f16 pairs)
    unsigned* pk_e = pk + 49152;                   // 1536 dwords (ctrl f16 pairs)

    float* out       = (float*)d_out;
    float* out_logit = out;                  // 147456
    float* out_mu    = out + 147456;         // 65536
    float* out_lv    = out + 212992;         // 65536
    float* out_beta  = out + 278528;         // 8192
    float* out_z     = out + 286720;         // 65536

    // pack recurrent weights to f16 pairs (thread-contiguous layouts)
    pack_w<<<198, 256, 0, stream>>>(whh_f, whh_b, whh_e, pk, pk_e);
    // input projections (parallel)
    gemm_k<<<dim3(128, 12), 256, 0, stream>>>(e, 256, wih_f, 256, bih_f, gi_f, 384, 384, 0);
    gemm_k<<<dim3(128, 12), 256, 0, stream>>>(e, 256, wih_b, 256, bih_b, gi_b, 384, 384, 0);
    gemm_k<<<dim3(128, 3),  256, 0, stream>>>(e, 256, wih_e, 512, bih_e, gie, 96, 96, 0);
    gemm_k<<<dim3(128, 2),  256, 0, stream>>>(e, 256, sw1_w, 296, sw1_b, swe, 64, 64, 0);
    // bidirectional GRU recurrence (single-barrier shfl-reduce, AGPR weights)
    gru_seq<<<32, 512, 0, stream>>>(gi_f, gi_b, pk, bhh_f, bhh_b, s_seq);
    // add s-part of controller GRU input projection
    gemm_k<<<dim3(128, 3), 256, 0, stream>>>(s_seq, 256, wih_e + 256, 512, nullptr, gie, 96, 96, 1);
    // controller h scan
    ctrl_h_scan<<<16, 128, 0, stream>>>(gie, pk_e, bhh_e, h_seq);
    // mu / logvar heads + h-part of switching-unit input
    gemm_k<<<dim3(128, 1), 256, 0, stream>>>(h_seq, 32, mu_w, 32, mu_b, out_mu, 8, 8, 0);
    gemm_k<<<dim3(128, 1), 256, 0, stream>>>(h_seq, 32, lv_w, 32, lv_b, out_lv, 8, 8, 0);
    gemm_k<<<dim3(128, 2), 256, 0, stream>>>(h_seq, 32, sw1_w + 256, 296, nullptr, swe, 64, 64, 1);
    // beta / z scan
    ctrl_z_scan<<<16, 64, 0, stream>>>(swe, sw1_w, sw2_w, sw2_b, eps, out_mu, out_lv, out_beta, out_z);
    // decoder hypernet + perturbation + LN + head
    decoder_final<<<1024, 256, 0, stream>>>(e, out_z, dec1_w, dec1_b, dec2_w, dec2_b,
                                            ln_g, ln_b, head_w, head_b, out_logit);
}

// Round 9
// 1337.962 us; speedup vs baseline: 1.1108x; 1.1108x over previous
//
#include <hip/hip_runtime.h>

#define TT 512
#define BB 16
#define DD 256
#define HHH 128
#define GG 32
#define ZZ 8
#define RR_ 16
#define NAA 18

typedef _Float16 h2v __attribute__((ext_vector_type(2)));

__device__ __forceinline__ float sigmoid_(float x) { return 1.f / (1.f + __expf(-x)); }
__device__ __forceinline__ float tanh_(float x) { float e = __expf(2.f * x); return 1.f - 2.f / (e + 1.f); }
__device__ __forceinline__ float dot4(float4 a, float4 b) {
    return a.x * b.x + a.y * b.y + a.z * b.z + a.w * b.w;
}
__device__ __forceinline__ h2v u2h2(unsigned u) { union { unsigned u; h2v h; } c; c.u = u; return c.h; }

// park a dword in an AGPR / fetch it back (opaque to the register allocator)
#define AGPR_STORE(a, v) asm volatile("v_accvgpr_write_b32 %0, %1" : "=a"(a) : "v"(v))
#define AGPR_LOAD(v, a)  asm volatile("v_accvgpr_read_b32 %0, %1" : "=v"(v) : "a"(a))

// ---------------------------------------------------------------------------
// Pack recurrent weights to f16 pairs.
// gru pk (R7 layout, 49152 dw): i -> (dir,s,q,j,m): half2(Wd[3q+j][32s+2m], +1)
// ctrl pk_e (1536 dw):          i -> (s,k,j,m):     half2(We[j*32+k][8s+2m], +1)
// ---------------------------------------------------------------------------
__global__ __launch_bounds__(256) void pack_w(
    const float* __restrict__ wf, const float* __restrict__ wb,
    const float* __restrict__ we,
    unsigned* __restrict__ pk, unsigned* __restrict__ pk_e)
{
    int i = blockIdx.x * 256 + threadIdx.x;          // 0 .. 50687
    if (i < 49152) {
        int dir = i / 24576; int r = i % 24576;
        int s = r / 6144;    int rem = r % 6144;
        int q = rem / 48;    int e = rem % 48;
        int j = e / 16;      int m = e % 16;
        const float* w = dir ? wb : wf;
        int row = 3 * q + j, k0 = 32 * s + 2 * m;
        union { _Float16 h[2]; unsigned u; } c;
        c.h[0] = (_Float16)w[row * 128 + k0];
        c.h[1] = (_Float16)w[row * 128 + k0 + 1];
        pk[i] = c.u;
    } else if (i < 50688) {
        int ie = i - 49152;
        int s = ie / 384;  int rem = ie % 384;
        int k = rem / 12;  int e = rem % 12;
        int j = e / 4;     int m = e % 4;
        int row = j * 32 + k, k0 = 8 * s + 2 * m;
        union { _Float16 h[2]; unsigned u; } c;
        c.h[0] = (_Float16)we[row * 32 + k0];
        c.h[1] = (_Float16)we[row * 32 + k0 + 1];
        pk_e[ie] = c.u;
    }
}

// ---------------------------------------------------------------------------
// Generic tiled GEMM (256 thr): Out[p][n] (+)= bias[n] + A[p]·W[n]
// ---------------------------------------------------------------------------
__global__ __launch_bounds__(256) void gemm_k(
    const float* __restrict__ A, int K, const float* __restrict__ W, int ldw,
    const float* __restrict__ bias, float* __restrict__ Out, int ldout, int N, int accFlag)
{
    __shared__ float At[64][36];
    __shared__ float Wt[32][36];
    int row0 = blockIdx.x * 64, n0 = blockIdx.y * 32;
    int tid = threadIdx.x;
    int tx = tid & 15, ty = tid >> 4;
    float acc[4][2] = {};
    for (int k0 = 0; k0 < K; k0 += 32) {
        #pragma unroll
        for (int i = 0; i < 8; ++i) {
            int idx = tid + i * 256; int rr = idx >> 5, kk = idx & 31;
            At[rr][kk] = A[(size_t)(row0 + rr) * K + k0 + kk];
        }
        #pragma unroll
        for (int i = 0; i < 4; ++i) {
            int idx = tid + i * 256; int nn = idx >> 5, kk = idx & 31;
            Wt[nn][kk] = (n0 + nn < N) ? W[(size_t)(n0 + nn) * ldw + k0 + kk] : 0.f;
        }
        __syncthreads();
        #pragma unroll
        for (int kk = 0; kk < 32; kk += 4) {
            float4 w0 = *(const float4*)&Wt[tx][kk];
            float4 w1 = *(const float4*)&Wt[tx + 16][kk];
            #pragma unroll
            for (int rr = 0; rr < 4; ++rr) {
                float4 av = *(const float4*)&At[ty * 4 + rr][kk];
                acc[rr][0] += dot4(av, w0);
                acc[rr][1] += dot4(av, w1);
            }
        }
        __syncthreads();
    }
    #pragma unroll
    for (int cc = 0; cc < 2; ++cc) {
        int n = n0 + tx + cc * 16;
        if (n < N) {
            float badd = bias ? bias[n] : 0.f;
            #pragma unroll
            for (int rr = 0; rr < 4; ++rr) {
                int row = row0 + ty * 4 + rr;
                float v = acc[rr][cc] + badd;
                if (accFlag) Out[(size_t)row * ldout + n] += v;
                else         Out[(size_t)row * ldout + n] = v;
            }
        }
    }
}

// ---------------------------------------------------------------------------
// Fused dispatch: blocks 0-31 = bidirectional GRU recurrence (exact R7
// structure: wave-aligned k-slices, LDS partial exchange, AGPR f16
// weights — best measured at 363 us). Blocks 32-415 = gie e-projection,
// blocks 416-671 = swe e-projection: independent of the GRU, they fill
// the 224 idle CUs and vanish from the serial timeline.
// ---------------------------------------------------------------------------
struct __align__(16) SmGru { _Float16 hbuf[128]; float part[4 * 384]; };
struct __align__(16) SmGemm { float At[64][36]; float Wt[32][36]; };
union __align__(16) SmU { SmGru g; SmGemm m; };

__device__ __forceinline__ void gemm_tile512(
    const float* __restrict__ A, int K, const float* __restrict__ W, int ldw,
    const float* __restrict__ bias, float* __restrict__ Out, int ldout, int N,
    int row0, int n0, SmGemm& sm)
{
    int tid = threadIdx.x;
    int tx = tid & 31, ty = tid >> 5;    // 32 cols x 16 row-groups (4 rows each)
    float acc[4] = {};
    for (int k0 = 0; k0 < K; k0 += 32) {
        #pragma unroll
        for (int i = 0; i < 4; ++i) {
            int idx = tid + i * 512; int rr = idx >> 5, kk = idx & 31;
            sm.At[rr][kk] = A[(size_t)(row0 + rr) * K + k0 + kk];
        }
        #pragma unroll
        for (int i = 0; i < 2; ++i) {
            int idx = tid + i * 512; int nn = idx >> 5, kk = idx & 31;
            sm.Wt[nn][kk] = (n0 + nn < N) ? W[(size_t)(n0 + nn) * ldw + k0 + kk] : 0.f;
        }
        __syncthreads();
        #pragma unroll
        for (int kk = 0; kk < 32; kk += 4) {
            float4 w0 = *(const float4*)&sm.Wt[tx][kk];
            #pragma unroll
            for (int rr = 0; rr < 4; ++rr) {
                float4 av = *(const float4*)&sm.At[ty * 4 + rr][kk];
                acc[rr] += dot4(av, w0);
            }
        }
        __syncthreads();
    }
    int n = n0 + tx;
    if (n < N) {
        float badd = bias ? bias[n] : 0.f;
        #pragma unroll
        for (int rr = 0; rr < 4; ++rr)
            Out[(size_t)(row0 + ty * 4 + rr) * ldout + n] = acc[rr] + badd;
    }
}

__global__ __launch_bounds__(512, 2) void gru_fused(
    const float* __restrict__ gi_f, const float* __restrict__ gi_b,
    const unsigned* __restrict__ pk,
    const float* __restrict__ bhh_f, const float* __restrict__ bhh_b,
    float* __restrict__ s_seq,
    const float* __restrict__ e,
    const float* __restrict__ wih_e, const float* __restrict__ bih_e, float* __restrict__ gie,
    const float* __restrict__ sw1_w, const float* __restrict__ sw1_b, float* __restrict__ swe)
{
    __shared__ SmU sm;
    int bx = blockIdx.x;
    if (bx >= 416) {                 // swe e-part: 8192x64, K=256
        int t = bx - 416;
        gemm_tile512(e, 256, sw1_w, 296, sw1_b, swe, 64, 64, (t & 127) * 64, (t >> 7) * 32, sm.m);
        return;
    }
    if (bx >= 32) {                  // gie e-part: 8192x96, K=256
        int t = bx - 32;
        gemm_tile512(e, 256, wih_e, 512, bih_e, gie, 96, 96, (t & 127) * 64, (t >> 7) * 32, sm.m);
        return;
    }

    // ---------------- GRU (R7 body) ----------------
    int dir = bx >> 4, b = bx & 15;
    const float* gi  = dir ? gi_b  : gi_f;
    const float* bhh = dir ? bhh_b : bhh_f;
    int tid = threadIdx.x;
    int s = tid >> 7;            // k-quarter (32 k = 16 half2), wave-uniform
    int q = tid & 127;           // row-triple: rows 3q..3q+2

    unsigned ag[48];
    {
        const uint4* wp = (const uint4*)(pk + ((size_t)(dir * 4 + s) * 128 + q) * 48);
        #pragma unroll
        for (int i = 0; i < 12; ++i) {
            uint4 u = wp[i];
            AGPR_STORE(ag[4 * i + 0], u.x);
            AGPR_STORE(ag[4 * i + 1], u.y);
            AGPR_STORE(ag[4 * i + 2], u.z);
            AGPR_STORE(ag[4 * i + 3], u.w);
        }
    }

    if (tid < 128) sm.g.hbuf[tid] = (_Float16)0.f;

    int k = tid;                 // gate-thread hidden index (tid < 128)
    float bhr = 0.f, bhz = 0.f, bhn = 0.f;
    float gra = 0.f, gza = 0.f, gna = 0.f;
    float grb = 0.f, gzb = 0.f, gnb = 0.f;
    float hreg = 0.f;
    if (tid < 128) {
        bhr = bhh[k]; bhz = bhh[128 + k]; bhn = bhh[256 + k];
        int t0 = dir ? 511 : 0;
        int t1 = dir ? 510 : 1;
        size_t p0 = (size_t)(b * TT + t0) * 384;
        size_t p1 = (size_t)(b * TT + t1) * 384;
        gra = gi[p0 + k]; gza = gi[p0 + 128 + k]; gna = gi[p0 + 256 + k];
        grb = gi[p1 + k]; gzb = gi[p1 + 128 + k]; gnb = gi[p1 + 256 + k];
    }
    __syncthreads();

    auto body = [&](int step, float& gr, float& gz, float& gn) {
        const uint4* hv4 = (const uint4*)((const unsigned*)sm.g.hbuf + s * 16);
        uint4 hA = hv4[0], hB = hv4[1], hC = hv4[2], hD = hv4[3];
        unsigned hw[16] = { hA.x, hA.y, hA.z, hA.w, hB.x, hB.y, hB.z, hB.w,
                            hC.x, hC.y, hC.z, hC.w, hD.x, hD.y, hD.z, hD.w };
        float a0 = 0.f, a1 = 0.f, a2 = 0.f;
        #pragma unroll
        for (int m = 0; m < 16; ++m) {
            unsigned w0, w1, w2;
            AGPR_LOAD(w0, ag[m]);
            AGPR_LOAD(w1, ag[16 + m]);
            AGPR_LOAD(w2, ag[32 + m]);
            h2v hh = u2h2(hw[m]);
            a0 = __builtin_amdgcn_fdot2(u2h2(w0), hh, a0, false);
            a1 = __builtin_amdgcn_fdot2(u2h2(w1), hh, a1, false);
            a2 = __builtin_amdgcn_fdot2(u2h2(w2), hh, a2, false);
        }
        int rb = s * 384 + q * 3;
        sm.g.part[rb] = a0; sm.g.part[rb + 1] = a1; sm.g.part[rb + 2] = a2;
        __syncthreads();

        if (tid < 128) {
            int t = dir ? (511 - step) : step;
            int p = b * TT + t;
            float ghr = bhr + sm.g.part[k]       + sm.g.part[384 + k]       + sm.g.part[768 + k]       + sm.g.part[1152 + k];
            float ghz = bhz + sm.g.part[128 + k] + sm.g.part[384 + 128 + k] + sm.g.part[768 + 128 + k] + sm.g.part[1152 + 128 + k];
            float ghn = bhn + sm.g.part[256 + k] + sm.g.part[384 + 256 + k] + sm.g.part[768 + 256 + k] + sm.g.part[1152 + 256 + k];
            float r = sigmoid_(gr + ghr);
            float z = sigmoid_(gz + ghz);
            float n = tanh_(gn + r * ghn);
            float hn = (1.f - z) * n + z * hreg;
            hreg = hn;
            sm.g.hbuf[k] = (_Float16)hn;
            s_seq[(size_t)p * 256 + dir * 128 + k] = hn;
            int s2 = step + 2;
            int tp = (s2 < 512) ? (dir ? (511 - s2) : s2) : t;
            size_t p2 = (size_t)(b * TT + tp) * 384;
            gr = gi[p2 + k]; gz = gi[p2 + 128 + k]; gn = gi[p2 + 256 + k];
        }
        __syncthreads();
    };

    for (int step = 0; step < 512; step += 2) {
        body(step,     gra, gza, gna);
        body(step + 1, grb, gzb, gnb);
    }
}

// ---------------------------------------------------------------------------
// Fused post-scan heads: mu (8), lv (8), sw1 h-part (64, accumulate) — one
// launch instead of three K=32 gemms.
// ---------------------------------------------------------------------------
__global__ __launch_bounds__(256) void heads_k(
    const float* __restrict__ h_seq,
    const float* __restrict__ mu_w, const float* __restrict__ mu_b,
    const float* __restrict__ lv_w, const float* __restrict__ lv_b,
    const float* __restrict__ sw1_w,
    float* __restrict__ out_mu, float* __restrict__ out_lv, float* __restrict__ swe)
{
    __shared__ __align__(16) float Ah[64][32];
    int row0 = blockIdx.x * 64;
    int tid = threadIdx.x;
    #pragma unroll
    for (int i = 0; i < 8; ++i) {
        int idx = tid + i * 256; int rr = idx >> 5, kk = idx & 31;
        Ah[rr][kk] = h_seq[(size_t)(row0 + rr) * 32 + kk];
    }
    __syncthreads();
    int r = tid >> 2, g = tid & 3;
    const float4* av = (const float4*)Ah[r];
    float4 a[8];
    #pragma unroll
    for (int i = 0; i < 8; ++i) a[i] = av[i];
    int row = row0 + r;
    for (int c = 0; c < 20; ++c) {
        int n = g * 20 + c;
        const float* wrow;
        if (n < 8)       wrow = mu_w + n * 32;
        else if (n < 16) wrow = lv_w + (n - 8) * 32;
        else             wrow = sw1_w + (size_t)(n - 16) * 296 + 256;
        const float4* wv = (const float4*)wrow;
        float acc = 0.f;
        #pragma unroll
        for (int i = 0; i < 8; ++i) acc += dot4(wv[i], a[i]);
        if (n < 8)       out_mu[row * 8 + n] = acc + mu_b[n];
        else if (n < 16) out_lv[row * 8 + (n - 8)] = acc + lv_b[n - 8];
        else             swe[(size_t)row * 64 + (n - 16)] += acc;
    }
}

// ---------------------------------------------------------------------------
// Controller h-scan. 16 WGs, 128 threads (2 waves). Single-barrier
// shfl-reduce structure: tid = k*4 + s, k<32, s = 8-wide slice.
// ---------------------------------------------------------------------------
__global__ __launch_bounds__(128, 1) void ctrl_h_scan(
    const float* __restrict__ gie, const unsigned* __restrict__ pk_e,
    const float* __restrict__ bhh_e, float* __restrict__ h_seq)
{
    int b = blockIdx.x, tid = threadIdx.x;
    int k = tid >> 2;            // hidden unit 0..31
    int s = tid & 3;             // slice 0..3 (8 h-values each)

    unsigned ag[12];
    {
        const uint4* wp = (const uint4*)(pk_e + ((size_t)(s * 32) + k) * 12);
        #pragma unroll
        for (int i = 0; i < 3; ++i) {
            uint4 u = wp[i];
            AGPR_STORE(ag[4 * i + 0], u.x);
            AGPR_STORE(ag[4 * i + 1], u.y);
            AGPR_STORE(ag[4 * i + 2], u.z);
            AGPR_STORE(ag[4 * i + 3], u.w);
        }
    }

    __shared__ __align__(16) _Float16 hb[2][32];
    if (tid < 32) hb[0][tid] = (_Float16)0.f;

    int pbase = b * TT;
    float bhr = 0.f, bhz = 0.f, bhn = 0.f;
    float g1a = 0.f, g2a = 0.f, g3a = 0.f, g1b = 0.f, g2b = 0.f, g3b = 0.f;
    float hreg = 0.f;
    if (s == 0) {
        bhr = bhh_e[k]; bhz = bhh_e[32 + k]; bhn = bhh_e[64 + k];
        size_t p0 = (size_t)pbase * 96, p1 = (size_t)(pbase + 1) * 96;
        g1a = gie[p0 + k]; g2a = gie[p0 + 32 + k]; g3a = gie[p0 + 64 + k];
        g1b = gie[p1 + k]; g2b = gie[p1 + 32 + k]; g3b = gie[p1 + 64 + k];
    }
    __syncthreads();

    int cur = 0;
    auto body = [&](int t, float& g1, float& g2, float& g3) {
        const uint4* hv = (const uint4*)(&hb[cur][0]) + s;
        uint4 h4 = hv[0];
        unsigned hw[4] = { h4.x, h4.y, h4.z, h4.w };
        float a0 = 0.f, a1 = 0.f, a2 = 0.f;
        #pragma unroll
        for (int m = 0; m < 4; ++m) {
            unsigned w0, w1, w2;
            AGPR_LOAD(w0, ag[m]);
            AGPR_LOAD(w1, ag[4 + m]);
            AGPR_LOAD(w2, ag[8 + m]);
            h2v hh = u2h2(hw[m]);
            a0 = __builtin_amdgcn_fdot2(u2h2(w0), hh, a0, false);
            a1 = __builtin_amdgcn_fdot2(u2h2(w1), hh, a1, false);
            a2 = __builtin_amdgcn_fdot2(u2h2(w2), hh, a2, false);
        }
        a0 += __shfl_xor(a0, 1); a0 += __shfl_xor(a0, 2);
        a1 += __shfl_xor(a1, 1); a1 += __shfl_xor(a1, 2);
        a2 += __shfl_xor(a2, 1); a2 += __shfl_xor(a2, 2);

        if (s == 0) {
            float r = sigmoid_(g1 + bhr + a0);
            float z = sigmoid_(g2 + bhz + a1);
            float n = tanh_(g3 + r * (bhn + a2));
            float hn = (1.f - z) * n + z * hreg;
            hreg = hn;
            hb[cur ^ 1][k] = (_Float16)hn;
            h_seq[(size_t)(pbase + t) * 32 + k] = hn;
            int t2 = (t + 2 < 512) ? t + 2 : t;
            size_t p2 = (size_t)(pbase + t2) * 96;
            g1 = gie[p2 + k]; g2 = gie[p2 + 32 + k]; g3 = gie[p2 + 64 + k];
        }
        __syncthreads();
        cur ^= 1;
    };

    for (int t = 0; t < 512; t += 2) {
        body(t,     g1a, g2a, g3a);
        body(t + 1, g1b, g2b, g3b);
    }
}

// ---------------------------------------------------------------------------
// Controller z/beta scan. 16 WGs, 1 wave, no LDS, no barriers.
// ---------------------------------------------------------------------------
__global__ __launch_bounds__(64, 1) void ctrl_z_scan(
    const float* __restrict__ hid_pre, const float* __restrict__ sw1_w,
    const float* __restrict__ sw2_w, const float* __restrict__ sw2_b,
    const float* __restrict__ eps, const float* __restrict__ mu_o,
    const float* __restrict__ lv_o, float* __restrict__ beta_o, float* __restrict__ z_o)
{
    int b = blockIdx.x, q = threadIdx.x;
    float wz[8];
    #pragma unroll
    for (int x = 0; x < 8; ++x) wz[x] = sw1_w[(size_t)q * 296 + 288 + x];
    float w2 = sw2_w[q];
    float bb = sw2_b[0];
    float zc = 0.f;
    int pbase = b * TT;

    float hpa = hid_pre[(size_t)pbase * 64 + q];
    float hpb = hid_pre[(size_t)(pbase + 1) * 64 + q];
    float mua = 0.f, lva = 0.f, epa = 0.f, mub = 0.f, lvb = 0.f, epb = 0.f;
    if (q < 8) {
        mua = mu_o[pbase * 8 + q]; lva = lv_o[pbase * 8 + q]; epa = eps[pbase * 8 + q];
        mub = mu_o[(pbase + 1) * 8 + q]; lvb = lv_o[(pbase + 1) * 8 + q]; epb = eps[(pbase + 1) * 8 + q];
    }

    auto body = [&](int t, float& hp, float& mu, float& lv, float& ep) {
        int p = pbase + t;
        float a = hp;
        #pragma unroll
        for (int x = 0; x < 8; ++x) a += wz[x] * __shfl(zc, x);
        float hid = tanh_(a);
        float prod = w2 * hid;
        #pragma unroll
        for (int m = 32; m >= 1; m >>= 1) prod += __shfl_xor(prod, m);
        float beta = sigmoid_(prod + bb);
        float zn = beta * (mu + __expf(0.5f * lv) * ep) + (1.f - beta) * zc;
        zc = zn;                      // meaningful in lanes 0-7 only
        if (q < 8) z_o[p * 8 + q] = zn;
        if (q == 0) beta_o[p] = beta;
        int t2 = (t + 2 < 512) ? t + 2 : t;
        hp = hid_pre[(size_t)(pbase + t2) * 64 + q];
        if (q < 8) {
            mu = mu_o[(pbase + t2) * 8 + q];
            lv = lv_o[(pbase + t2) * 8 + q];
            ep = eps[(pbase + t2) * 8 + q];
        }
    };

    for (int t = 0; t < 512; t += 2) {
        body(t,     hpa, mua, lva, epa);
        body(t + 1, hpb, mub, lvb, epb);
    }
}

// ---------------------------------------------------------------------------
// Decoder hypernet + rank-R perturbation + LayerNorm + head. P=8/WG.
// ---------------------------------------------------------------------------
__global__ __launch_bounds__(256, 3) void decoder_final(
    const float* __restrict__ e_seq, const float* __restrict__ z_o,
    const float* __restrict__ dec1_w, const float* __restrict__ dec1_b,
    const float* __restrict__ dec2_w, const float* __restrict__ dec2_b,
    const float* __restrict__ ln_g, const float* __restrict__ ln_b,
    const float* __restrict__ head_w, const float* __restrict__ head_b,
    float* __restrict__ logits)
{
    __shared__ __align__(16) float e_l[8][256];
    __shared__ __align__(16) float hmid[8][32];
    __shared__ float zl[8][8];
    __shared__ float tmpw[8][16];
    __shared__ __align__(16) float partb[2048];
    __shared__ float red1[8][16];
    __shared__ float red2[8][16];
    __shared__ float stats[8][2];
    int tid = threadIdx.x;
    int p0 = blockIdx.x * 8;

    {
        const float4* eg = (const float4*)(e_seq + (size_t)p0 * 256);
        float4* el4 = (float4*)&e_l[0][0];
        el4[tid] = eg[tid];
        el4[tid + 256] = eg[tid + 256];
        if (tid < 64) ((float*)zl)[tid] = z_o[p0 * 8 + tid];
    }
    __syncthreads();
    {
        int pp = tid >> 5, g = tid & 31;
        float a = dec1_b[g];
        #pragma unroll
        for (int x = 0; x < 8; ++x) a += dec1_w[g * 8 + x] * zl[pp][x];
        hmid[pp][g] = tanh_(a);
    }
    __syncthreads();
    // ---- pass B: tmp[pp][r] = sum_d Bm[d,r]*e[d]
    {
        int r = tid & 15, dgrp = tid >> 4;
        float acc[8];
        #pragma unroll
        for (int pp = 0; pp < 8; ++pp) acc[pp] = 0.f;
        for (int iblk = 0; iblk < 8; ++iblk) {
            float4 wr[2][8]; float wb[2]; int dd[2];
            #pragma unroll
            for (int ii = 0; ii < 2; ++ii) {
                int d = dgrp + 16 * (iblk * 2 + ii);
                dd[ii] = d;
                int row = 4096 + d * 16 + r;
                const float4* wp = (const float4*)(dec2_w + (size_t)row * 32);
                #pragma unroll
                for (int g = 0; g < 8; ++g) wr[ii][g] = wp[g];
                wb[ii] = dec2_b[row];
            }
            #pragma unroll 1
            for (int pp = 0; pp < 8; ++pp) {
                const float4* hv = (const float4*)hmid[pp];
                float b0 = wb[0], b1 = wb[1];
                #pragma unroll
                for (int g = 0; g < 8; ++g) {
                    float4 hh = hv[g];
                    b0 += dot4(wr[0][g], hh);
                    b1 += dot4(wr[1][g], hh);
                }
                acc[pp] += b0 * e_l[pp][dd[0]] + b1 * e_l[pp][dd[1]];
            }
        }
        #pragma unroll
        for (int pp = 0; pp < 8; ++pp) partb[(pp * 16 + r) * 16 + dgrp] = acc[pp];
    }
    __syncthreads();
    if (tid < 128) {
        int pp = tid >> 4, rr = tid & 15;
        float s = 0.f;
        #pragma unroll
        for (int dg = 0; dg < 16; ++dg) s += partb[(pp * 16 + rr) * 16 + dg];
        tmpw[pp][rr] = s;
    }
    __syncthreads();
    // ---- pass A
    {
        int d = tid;
        float po[8];
        #pragma unroll
        for (int pp = 0; pp < 8; ++pp) po[pp] = e_l[pp][d];
        for (int rblk = 0; rblk < 8; ++rblk) {
            float4 wr[2][8]; float wb[2];
            #pragma unroll
            for (int ii = 0; ii < 2; ++ii) {
                int row = d * 16 + rblk * 2 + ii;
                const float4* wp = (const float4*)(dec2_w + (size_t)row * 32);
                #pragma unroll
                for (int g = 0; g < 8; ++g) wr[ii][g] = wp[g];
                wb[ii] = dec2_b[row];
            }
            #pragma unroll 1
            for (int pp = 0; pp < 8; ++pp) {
                const float4* hv = (const float4*)hmid[pp];
                float a0 = wb[0], a1 = wb[1];
                #pragma unroll
                for (int g = 0; g < 8; ++g) {
                    float4 hh = hv[g];
                    a0 += dot4(wr[0][g], hh);
                    a1 += dot4(wr[1][g], hh);
                }
                po[pp] += a0 * tmpw[pp][rblk * 2] + a1 * tmpw[pp][rblk * 2 + 1];
            }
        }
        #pragma unroll
        for (int pp = 0; pp < 8; ++pp) partb[pp * 256 + d] = po[pp];
    }
    __syncthreads();
    if (tid < 128) {
        int pp = tid >> 4, c = tid & 15;
        float s = 0.f, s2 = 0.f;
        #pragma unroll
        for (int i = 0; i < 16; ++i) { float v = partb[pp * 256 + c * 16 + i]; s += v; s2 += v * v; }
        red1[pp][c] = s; red2[pp][c] = s2;
    }
    __syncthreads();
    if (tid < 8) {
        float s = 0.f, s2 = 0.f;
        #pragma unroll
        for (int c = 0; c < 16; ++c) { s += red1[tid][c]; s2 += red2[tid][c]; }
        float mean = s * (1.f / 256.f);
        float var = s2 * (1.f / 256.f) - mean * mean;
        stats[tid][0] = mean;
        stats[tid][1] = rsqrtf(var + 1e-5f);
    }
    __syncthreads();
    {
        int d = tid;
        float g = ln_g[d], bln = ln_b[d];
        #pragma unroll
        for (int pp = 0; pp < 8; ++pp) {
            float v = (partb[pp * 256 + d] - stats[pp][0]) * stats[pp][1];
            partb[pp * 256 + d] = v * g + bln;
        }
    }
    __syncthreads();
    if (tid < 144) {
        int pp = tid / 18, na = tid - pp * 18;
        float a = head_b[na];
        for (int d2 = 0; d2 < 256; ++d2)
            a += partb[pp * 256 + d2] * head_w[na * 256 + d2];
        logits[(size_t)(p0 + pp) * 18 + na] = a;
    }
}

// ---------------------------------------------------------------------------
extern "C" void kernel_launch(void* const* d_in, const int* in_sizes, int n_in,
                              void* d_out, int out_size, void* d_ws, size_t ws_size,
                              hipStream_t stream) {
    (void)in_sizes; (void)n_in; (void)out_size; (void)ws_size;
    const float* e     = (const float*)d_in[0];
    const float* eps   = (const float*)d_in[1];
    const float* wih_f = (const float*)d_in[2];
    const float* whh_f = (const float*)d_in[3];
    const float* bih_f = (const float*)d_in[4];
    const float* bhh_f = (const float*)d_in[5];
    const float* wih_b = (const float*)d_in[6];
    const float* whh_b = (const float*)d_in[7];
    const float* bih_b = (const float*)d_in[8];
    const float* bhh_b = (const float*)d_in[9];
    const float* wih_e = (const float*)d_in[10];
    const float* whh_e = (const float*)d_in[11];
    const float* bih_e = (const float*)d_in[12];
    const float* bhh_e = (const float*)d_in[13];
    const float* mu_w  = (const float*)d_in[14];
    const float* mu_b  = (const float*)d_in[15];
    const float* lv_w  = (const float*)d_in[16];
    const float* lv_b  = (const float*)d_in[17];
    const float* sw1_w = (const float*)d_in[18];
    const float* sw1_b = (const float*)d_in[19];
    const float* sw2_w = (const float*)d_in[20];
    const float* sw2_b = (const float*)d_in[21];
    const float* dec1_w = (const float*)d_in[22];
    const float* dec1_b = (const float*)d_in[23];
    const float* dec2_w = (const float*)d_in[24];
    const float* dec2_b = (const float*)d_in[25];
    const float* ln_g  = (const float*)d_in[26];
    const float* ln_b  = (const float*)d_in[27];
    const float* head_w = (const float*)d_in[28];
    const float* head_b = (const float*)d_in[29];

    float* ws    = (float*)d_ws;
    float* gi_f  = ws;                       // 8192*384
    float* gi_b  = gi_f + 3145728;           // 8192*384
    float* gie   = gi_b + 3145728;           // 8192*96
    float* swe   = gie + 786432;             // 8192*64 (hid_pre)
    float* s_seq = swe + 524288;             // 8192*256
    float* h_seq = s_seq + 2097152;          // 8192*32
    unsigned* pk   = (unsigned*)(h_seq + 262144);  // 49152 dwords (gru f16 pairs)
    unsigned* pk_e = pk + 49152;                   // 1536 dwords (ctrl f16 pairs)

    float* out       = (float*)d_out;
    float* out_logit = out;                  // 147456
    float* out_mu    = out + 147456;         // 65536
    float* out_lv    = out + 212992;         // 65536
    float* out_beta  = out + 278528;         // 8192
    float* out_z     = out + 286720;         // 65536

    // pack recurrent weights to f16 pairs (thread-contiguous layouts)
    pack_w<<<198, 256, 0, stream>>>(whh_f, whh_b, whh_e, pk, pk_e);
    // big input projections (must precede GRU)
    gemm_k<<<dim3(128, 12), 256, 0, stream>>>(e, 256, wih_f, 256, bih_f, gi_f, 384, 384, 0);
    gemm_k<<<dim3(128, 12), 256, 0, stream>>>(e, 256, wih_b, 256, bih_b, gi_b, 384, 384, 0);
    // GRU recurrence fused with the independent gie/swe e-projections
    gru_fused<<<672, 512, 0, stream>>>(gi_f, gi_b, pk, bhh_f, bhh_b, s_seq,
                                       e, wih_e, bih_e, gie, sw1_w, sw1_b, swe);
    // add s-part of controller GRU input projection
    gemm_k<<<dim3(128, 3), 256, 0, stream>>>(s_seq, 256, wih_e + 256, 512, nullptr, gie, 96, 96, 1);
    // controller h scan
    ctrl_h_scan<<<16, 128, 0, stream>>>(gie, pk_e, bhh_e, h_seq);
    // fused mu / logvar / switching-unit h-part
    heads_k<<<128, 256, 0, stream>>>(h_seq, mu_w, mu_b, lv_w, lv_b, sw1_w, out_mu, out_lv, swe);
    // beta / z scan
    ctrl_z_scan<<<16, 64, 0, stream>>>(swe, sw1_w, sw2_w, sw2_b, eps, out_mu, out_lv, out_beta, out_z);
    // decoder hypernet + perturbation + LN + head
    decoder_final<<<1024, 256, 0, stream>>>(e, out_z, dec1_w, dec1_b, dec2_w, dec2_b,
                                            ln_g, ln_b, head_w, head_b, out_logit);
}

// Round 10
// 1224.253 us; speedup vs baseline: 1.2140x; 1.0929x over previous
//
#include <hip/hip_runtime.h>

#define TT 512
#define BB 16
#define DD 256
#define HHH 128
#define GG 32
#define ZZ 8
#define RR_ 16
#define NAA 18

typedef _Float16 h2v __attribute__((ext_vector_type(2)));
typedef __attribute__((ext_vector_type(4))) float f4;
typedef __attribute__((ext_vector_type(4))) int i4;

__device__ __forceinline__ float sigmoid_(float x) { return 1.f / (1.f + __expf(-x)); }
__device__ __forceinline__ float tanh_(float x) { float e = __expf(2.f * x); return 1.f - 2.f / (e + 1.f); }
__device__ __forceinline__ float dot4(float4 a, float4 b) {
    return a.x * b.x + a.y * b.y + a.z * b.z + a.w * b.w;
}
__device__ __forceinline__ h2v u2h2(unsigned u) { union { unsigned u; h2v h; } c; c.u = u; return c.h; }

// park a dword in an AGPR / fetch it back (opaque to the register allocator)
#define AGPR_STORE(a, v) asm volatile("v_accvgpr_write_b32 %0, %1" : "=a"(a) : "v"(v))
#define AGPR_LOAD(v, a)  asm volatile("v_accvgpr_read_b32 %0, %1" : "=v"(v) : "a"(a))

// ---------------------------------------------------------------------------
// Pack recurrent weights to f16.
// gru pk (MFMA B-frag layout, 49152 dw):
//   i = ((((dir*8+w)*3+T)*4+kt)*64+lane)*4+jd
//   -> half2( W[T*128+16w+(lane&15)][kt*32+(lane>>4)*8+2jd], +1 )
// ctrl pk_e (1536 dw): i -> (s,k,j,m): half2(We[j*32+k][8s+2m], +1)
// ---------------------------------------------------------------------------
__global__ __launch_bounds__(256) void pack_w(
    const float* __restrict__ wf, const float* __restrict__ wb,
    const float* __restrict__ we,
    unsigned* __restrict__ pk, unsigned* __restrict__ pk_e)
{
    int i = blockIdx.x * 256 + threadIdx.x;          // 0 .. 50687
    if (i < 49152) {
        int dir = i / 24576; int r = i % 24576;
        int w = r / 3072;    int r2 = r % 3072;
        int T = r2 / 1024;   int r3 = r2 % 1024;
        int kt = r3 / 256;   int r4 = r3 % 256;
        int lane = r4 / 4;   int jd = r4 % 4;
        const float* wsrc = dir ? wb : wf;
        int row = T * 128 + 16 * w + (lane & 15);
        int k0 = kt * 32 + (lane >> 4) * 8 + 2 * jd;
        union { _Float16 h[2]; unsigned u; } c;
        c.h[0] = (_Float16)wsrc[row * 128 + k0];
        c.h[1] = (_Float16)wsrc[row * 128 + k0 + 1];
        pk[i] = c.u;
    } else if (i < 50688) {
        int ie = i - 49152;
        int s = ie / 384;  int rem = ie % 384;
        int k = rem / 12;  int e = rem % 12;
        int j = e / 4;     int m = e % 4;
        int row = j * 32 + k, k0 = 8 * s + 2 * m;
        union { _Float16 h[2]; unsigned u; } c;
        c.h[0] = (_Float16)we[row * 32 + k0];
        c.h[1] = (_Float16)we[row * 32 + k0 + 1];
        pk_e[ie] = c.u;
    }
}

// ---------------------------------------------------------------------------
// Generic tiled GEMM (256 thr): Out[p][n] (+)= bias[n] + A[p]·W[n]
// ---------------------------------------------------------------------------
__global__ __launch_bounds__(256) void gemm_k(
    const float* __restrict__ A, int K, const float* __restrict__ W, int ldw,
    const float* __restrict__ bias, float* __restrict__ Out, int ldout, int N, int accFlag)
{
    __shared__ float At[64][36];
    __shared__ float Wt[32][36];
    int row0 = blockIdx.x * 64, n0 = blockIdx.y * 32;
    int tid = threadIdx.x;
    int tx = tid & 15, ty = tid >> 4;
    float acc[4][2] = {};
    for (int k0 = 0; k0 < K; k0 += 32) {
        #pragma unroll
        for (int i = 0; i < 8; ++i) {
            int idx = tid + i * 256; int rr = idx >> 5, kk = idx & 31;
            At[rr][kk] = A[(size_t)(row0 + rr) * K + k0 + kk];
        }
        #pragma unroll
        for (int i = 0; i < 4; ++i) {
            int idx = tid + i * 256; int nn = idx >> 5, kk = idx & 31;
            Wt[nn][kk] = (n0 + nn < N) ? W[(size_t)(n0 + nn) * ldw + k0 + kk] : 0.f;
        }
        __syncthreads();
        #pragma unroll
        for (int kk = 0; kk < 32; kk += 4) {
            float4 w0 = *(const float4*)&Wt[tx][kk];
            float4 w1 = *(const float4*)&Wt[tx + 16][kk];
            #pragma unroll
            for (int rr = 0; rr < 4; ++rr) {
                float4 av = *(const float4*)&At[ty * 4 + rr][kk];
                acc[rr][0] += dot4(av, w0);
                acc[rr][1] += dot4(av, w1);
            }
        }
        __syncthreads();
    }
    #pragma unroll
    for (int cc = 0; cc < 2; ++cc) {
        int n = n0 + tx + cc * 16;
        if (n < N) {
            float badd = bias ? bias[n] : 0.f;
            #pragma unroll
            for (int rr = 0; rr < 4; ++rr) {
                int row = row0 + ty * 4 + rr;
                float v = acc[rr][cc] + badd;
                if (accFlag) Out[(size_t)row * ldout + n] += v;
                else         Out[(size_t)row * ldout + n] = v;
            }
        }
    }
}

// ---------------------------------------------------------------------------
// Fused dispatch: blocks 0-31 = GRU recurrence via MFMA; blocks 32-415 =
// gie e-projection; blocks 416-671 = swe e-projection (riders on idle CUs).
//
// GRU-MFMA: per step gh(384) = h(128)·W^T as 12 v_mfma_f32_16x16x32_f16
// per wave (wave w owns n-tiles {w,8+w,16+w} = r/z/n rows 16w..16w+15).
// Every lane loads the SAME per-quad h-fragment -> all 16 A-rows are
// copies of h -> every D row equals gh (no masking needed). B-frags are
// permanently AGPR-resident (pinned "+a", consumed via "a" operand —
// zero per-step weight movement; replaces R7-R9's 96 VALU ops/thread).
// Gates in-lane (lanes 0-15/wave, reg 0); h f16 double-buffered in LDS;
// ONE barrier/step.
// ---------------------------------------------------------------------------
struct __align__(16) SmGru { _Float16 hb[2][128]; };
struct __align__(16) SmGemm { float At[64][36]; float Wt[32][36]; };
union __align__(16) SmU { SmGru g; SmGemm m; };

__device__ __forceinline__ void gemm_tile512(
    const float* __restrict__ A, int K, const float* __restrict__ W, int ldw,
    const float* __restrict__ bias, float* __restrict__ Out, int ldout, int N,
    int row0, int n0, SmGemm& sm)
{
    int tid = threadIdx.x;
    int tx = tid & 31, ty = tid >> 5;    // 32 cols x 16 row-groups (4 rows each)
    float acc[4] = {};
    for (int k0 = 0; k0 < K; k0 += 32) {
        #pragma unroll
        for (int i = 0; i < 4; ++i) {
            int idx = tid + i * 512; int rr = idx >> 5, kk = idx & 31;
            sm.At[rr][kk] = A[(size_t)(row0 + rr) * K + k0 + kk];
        }
        #pragma unroll
        for (int i = 0; i < 2; ++i) {
            int idx = tid + i * 512; int nn = idx >> 5, kk = idx & 31;
            sm.Wt[nn][kk] = (n0 + nn < N) ? W[(size_t)(n0 + nn) * ldw + k0 + kk] : 0.f;
        }
        __syncthreads();
        #pragma unroll
        for (int kk = 0; kk < 32; kk += 4) {
            float4 w0 = *(const float4*)&sm.Wt[tx][kk];
            #pragma unroll
            for (int rr = 0; rr < 4; ++rr) {
                float4 av = *(const float4*)&sm.At[ty * 4 + rr][kk];
                acc[rr] += dot4(av, w0);
            }
        }
        __syncthreads();
    }
    int n = n0 + tx;
    if (n < N) {
        float badd = bias ? bias[n] : 0.f;
        #pragma unroll
        for (int rr = 0; rr < 4; ++rr)
            Out[(size_t)(row0 + ty * 4 + rr) * ldout + n] = acc[rr] + badd;
    }
}

__global__ __launch_bounds__(512, 2) void gru_fused(
    const float* __restrict__ gi_f, const float* __restrict__ gi_b,
    const unsigned* __restrict__ pk,
    const float* __restrict__ bhh_f, const float* __restrict__ bhh_b,
    float* __restrict__ s_seq,
    const float* __restrict__ e,
    const float* __restrict__ wih_e, const float* __restrict__ bih_e, float* __restrict__ gie,
    const float* __restrict__ sw1_w, const float* __restrict__ sw1_b, float* __restrict__ swe)
{
    __shared__ SmU sm;
    int bx = blockIdx.x;
    if (bx >= 416) {                 // swe e-part: 8192x64, K=256
        int t = bx - 416;
        gemm_tile512(e, 256, sw1_w, 296, sw1_b, swe, 64, 64, (t & 127) * 64, (t >> 7) * 32, sm.m);
        return;
    }
    if (bx >= 32) {                  // gie e-part: 8192x96, K=256
        int t = bx - 32;
        gemm_tile512(e, 256, wih_e, 512, bih_e, gie, 96, 96, (t & 127) * 64, (t >> 7) * 32, sm.m);
        return;
    }

    // ---------------- GRU (MFMA body) ----------------
    int dir = bx >> 4, b = bx & 15;
    const float* gi  = dir ? gi_b  : gi_f;
    const float* bhh = dir ? bhh_b : bhh_f;
    int tid = threadIdx.x;
    int w = tid >> 6;            // wave 0..7
    int lane = tid & 63;
    int quad = lane >> 4;
    int c = lane & 15;
    int j = 16 * w + c;          // hidden unit for gate lanes (lane < 16)

    // B-fragments: 12 x 4 dwords, permanently AGPR-resident
    i4 bf[3][4];
    #pragma unroll
    for (int T = 0; T < 3; ++T)
        #pragma unroll
        for (int kt = 0; kt < 4; ++kt)
            bf[T][kt] = *(const i4*)(pk + (size_t)((((dir * 8 + w) * 3 + T) * 4 + kt) * 64 + lane) * 4);
    #pragma unroll
    for (int T = 0; T < 3; ++T)
        #pragma unroll
        for (int kt = 0; kt < 4; ++kt)
            asm volatile("" : "+a"(bf[T][kt]));

    if (tid < 128) sm.g.hb[0][tid] = (_Float16)0.f;

    float bhr = 0.f, bhz = 0.f, bhn = 0.f;
    float gra = 0.f, gza = 0.f, gna = 0.f;
    float grb = 0.f, gzb = 0.f, gnb = 0.f;
    float hreg = 0.f;
    if (lane < 16) {
        bhr = bhh[j]; bhz = bhh[128 + j]; bhn = bhh[256 + j];
        int t0 = dir ? 511 : 0;
        int t1 = dir ? 510 : 1;
        size_t p0 = (size_t)(b * TT + t0) * 384;
        size_t p1 = (size_t)(b * TT + t1) * 384;
        gra = gi[p0 + j]; gza = gi[p0 + 128 + j]; gna = gi[p0 + 256 + j];
        grb = gi[p1 + j]; gzb = gi[p1 + 128 + j]; gnb = gi[p1 + 256 + j];
    }
    __syncthreads();

    int cur = 0;
    auto body = [&](int step, float& gr, float& gz, float& gn) {
        // A-fragment: per-quad 16B broadcast of h (all 16 rows = copies of h)
        i4 af[4];
        #pragma unroll
        for (int kt = 0; kt < 4; ++kt)
            af[kt] = *(const i4*)(&sm.g.hb[cur][kt * 32 + quad * 8]);
        f4 accr = {0.f, 0.f, 0.f, 0.f};
        f4 accz = {0.f, 0.f, 0.f, 0.f};
        f4 accn = {0.f, 0.f, 0.f, 0.f};
        asm volatile("s_nop 3");
        #pragma unroll
        for (int kt = 0; kt < 4; ++kt) {
            asm volatile("v_mfma_f32_16x16x32_f16 %0, %1, %2, %0" : "+v"(accr) : "v"(af[kt]), "a"(bf[0][kt]));
            asm volatile("v_mfma_f32_16x16x32_f16 %0, %1, %2, %0" : "+v"(accz) : "v"(af[kt]), "a"(bf[1][kt]));
            asm volatile("v_mfma_f32_16x16x32_f16 %0, %1, %2, %0" : "+v"(accn) : "v"(af[kt]), "a"(bf[2][kt]));
        }
        asm volatile("s_nop 7\n\ts_nop 7");
        if (lane < 16) {
            int t = dir ? (511 - step) : step;
            int p = b * TT + t;
            float r = sigmoid_(gr + bhr + accr[0]);
            float z = sigmoid_(gz + bhz + accz[0]);
            float n = tanh_(gn + r * (bhn + accn[0]));
            float hn = (1.f - z) * n + z * hreg;
            hreg = hn;
            sm.g.hb[cur ^ 1][j] = (_Float16)hn;
            s_seq[(size_t)p * 256 + dir * 128 + j] = hn;
            int s2 = step + 2;
            int tp = (s2 < 512) ? (dir ? (511 - s2) : s2) : t;
            size_t p2 = (size_t)(b * TT + tp) * 384;
            gr = gi[p2 + j]; gz = gi[p2 + 128 + j]; gn = gi[p2 + 256 + j];
        }
        __syncthreads();
        cur ^= 1;
    };

    for (int step = 0; step < 512; step += 2) {
        body(step,     gra, gza, gna);
        body(step + 1, grb, gzb, gnb);
    }
}

// ---------------------------------------------------------------------------
// Fused post-scan heads: mu (8), lv (8), sw1 h-part (64, accumulate).
// ---------------------------------------------------------------------------
__global__ __launch_bounds__(256) void heads_k(
    const float* __restrict__ h_seq,
    const float* __restrict__ mu_w, const float* __restrict__ mu_b,
    const float* __restrict__ lv_w, const float* __restrict__ lv_b,
    const float* __restrict__ sw1_w,
    float* __restrict__ out_mu, float* __restrict__ out_lv, float* __restrict__ swe)
{
    __shared__ __align__(16) float Ah[64][32];
    int row0 = blockIdx.x * 64;
    int tid = threadIdx.x;
    #pragma unroll
    for (int i = 0; i < 8; ++i) {
        int idx = tid + i * 256; int rr = idx >> 5, kk = idx & 31;
        Ah[rr][kk] = h_seq[(size_t)(row0 + rr) * 32 + kk];
    }
    __syncthreads();
    int r = tid >> 2, g = tid & 3;
    const float4* av = (const float4*)Ah[r];
    float4 a[8];
    #pragma unroll
    for (int i = 0; i < 8; ++i) a[i] = av[i];
    int row = row0 + r;
    for (int c = 0; c < 20; ++c) {
        int n = g * 20 + c;
        const float* wrow;
        if (n < 8)       wrow = mu_w + n * 32;
        else if (n < 16) wrow = lv_w + (n - 8) * 32;
        else             wrow = sw1_w + (size_t)(n - 16) * 296 + 256;
        const float4* wv = (const float4*)wrow;
        float acc = 0.f;
        #pragma unroll
        for (int i = 0; i < 8; ++i) acc += dot4(wv[i], a[i]);
        if (n < 8)       out_mu[row * 8 + n] = acc + mu_b[n];
        else if (n < 16) out_lv[row * 8 + (n - 8)] = acc + lv_b[n - 8];
        else             swe[(size_t)row * 64 + (n - 16)] += acc;
    }
}

// ---------------------------------------------------------------------------
// Controller h-scan. 16 WGs, 128 threads (2 waves). Single-barrier
// shfl-reduce structure: tid = k*4 + s, k<32, s = 8-wide slice.
// ---------------------------------------------------------------------------
__global__ __launch_bounds__(128, 1) void ctrl_h_scan(
    const float* __restrict__ gie, const unsigned* __restrict__ pk_e,
    const float* __restrict__ bhh_e, float* __restrict__ h_seq)
{
    int b = blockIdx.x, tid = threadIdx.x;
    int k = tid >> 2;            // hidden unit 0..31
    int s = tid & 3;             // slice 0..3 (8 h-values each)

    unsigned ag[12];
    {
        const uint4* wp = (const uint4*)(pk_e + ((size_t)(s * 32) + k) * 12);
        #pragma unroll
        for (int i = 0; i < 3; ++i) {
            uint4 u = wp[i];
            AGPR_STORE(ag[4 * i + 0], u.x);
            AGPR_STORE(ag[4 * i + 1], u.y);
            AGPR_STORE(ag[4 * i + 2], u.z);
            AGPR_STORE(ag[4 * i + 3], u.w);
        }
    }

    __shared__ __align__(16) _Float16 hb[2][32];
    if (tid < 32) hb[0][tid] = (_Float16)0.f;

    int pbase = b * TT;
    float bhr = 0.f, bhz = 0.f, bhn = 0.f;
    float g1a = 0.f, g2a = 0.f, g3a = 0.f, g1b = 0.f, g2b = 0.f, g3b = 0.f;
    float hreg = 0.f;
    if (s == 0) {
        bhr = bhh_e[k]; bhz = bhh_e[32 + k]; bhn = bhh_e[64 + k];
        size_t p0 = (size_t)pbase * 96, p1 = (size_t)(pbase + 1) * 96;
        g1a = gie[p0 + k]; g2a = gie[p0 + 32 + k]; g3a = gie[p0 + 64 + k];
        g1b = gie[p1 + k]; g2b = gie[p1 + 32 + k]; g3b = gie[p1 + 64 + k];
    }
    __syncthreads();

    int cur = 0;
    auto body = [&](int t, float& g1, float& g2, float& g3) {
        const uint4* hv = (const uint4*)(&hb[cur][0]) + s;
        uint4 h4 = hv[0];
        unsigned hw[4] = { h4.x, h4.y, h4.z, h4.w };
        float a0 = 0.f, a1 = 0.f, a2 = 0.f;
        #pragma unroll
        for (int m = 0; m < 4; ++m) {
            unsigned w0, w1, w2;
            AGPR_LOAD(w0, ag[m]);
            AGPR_LOAD(w1, ag[4 + m]);
            AGPR_LOAD(w2, ag[8 + m]);
            h2v hh = u2h2(hw[m]);
            a0 = __builtin_amdgcn_fdot2(u2h2(w0), hh, a0, false);
            a1 = __builtin_amdgcn_fdot2(u2h2(w1), hh, a1, false);
            a2 = __builtin_amdgcn_fdot2(u2h2(w2), hh, a2, false);
        }
        a0 += __shfl_xor(a0, 1); a0 += __shfl_xor(a0, 2);
        a1 += __shfl_xor(a1, 1); a1 += __shfl_xor(a1, 2);
        a2 += __shfl_xor(a2, 1); a2 += __shfl_xor(a2, 2);

        if (s == 0) {
            float r = sigmoid_(g1 + bhr + a0);
            float z = sigmoid_(g2 + bhz + a1);
            float n = tanh_(g3 + r * (bhn + a2));
            float hn = (1.f - z) * n + z * hreg;
            hreg = hn;
            hb[cur ^ 1][k] = (_Float16)hn;
            h_seq[(size_t)(pbase + t) * 32 + k] = hn;
            int t2 = (t + 2 < 512) ? t + 2 : t;
            size_t p2 = (size_t)(pbase + t2) * 96;
            g1 = gie[p2 + k]; g2 = gie[p2 + 32 + k]; g3 = gie[p2 + 64 + k];
        }
        __syncthreads();
        cur ^= 1;
    };

    for (int t = 0; t < 512; t += 2) {
        body(t,     g1a, g2a, g3a);
        body(t + 1, g1b, g2b, g3b);
    }
}

// ---------------------------------------------------------------------------
// Controller z/beta scan. 16 WGs, 1 wave, no LDS, no barriers.
// ---------------------------------------------------------------------------
__global__ __launch_bounds__(64, 1) void ctrl_z_scan(
    const float* __restrict__ hid_pre, const float* __restrict__ sw1_w,
    const float* __restrict__ sw2_w, const float* __restrict__ sw2_b,
    const float* __restrict__ eps, const float* __restrict__ mu_o,
    const float* __restrict__ lv_o, float* __restrict__ beta_o, float* __restrict__ z_o)
{
    int b = blockIdx.x, q = threadIdx.x;
    float wz[8];
    #pragma unroll
    for (int x = 0; x < 8; ++x) wz[x] = sw1_w[(size_t)q * 296 + 288 + x];
    float w2 = sw2_w[q];
    float bb = sw2_b[0];
    float zc = 0.f;
    int pbase = b * TT;

    float hpa = hid_pre[(size_t)pbase * 64 + q];
    float hpb = hid_pre[(size_t)(pbase + 1) * 64 + q];
    float mua = 0.f, lva = 0.f, epa = 0.f, mub = 0.f, lvb = 0.f, epb = 0.f;
    if (q < 8) {
        mua = mu_o[pbase * 8 + q]; lva = lv_o[pbase * 8 + q]; epa = eps[pbase * 8 + q];
        mub = mu_o[(pbase + 1) * 8 + q]; lvb = lv_o[(pbase + 1) * 8 + q]; epb = eps[(pbase + 1) * 8 + q];
    }

    auto body = [&](int t, float& hp, float& mu, float& lv, float& ep) {
        int p = pbase + t;
        float a = hp;
        #pragma unroll
        for (int x = 0; x < 8; ++x) a += wz[x] * __shfl(zc, x);
        float hid = tanh_(a);
        float prod = w2 * hid;
        #pragma unroll
        for (int m = 32; m >= 1; m >>= 1) prod += __shfl_xor(prod, m);
        float beta = sigmoid_(prod + bb);
        float zn = beta * (mu + __expf(0.5f * lv) * ep) + (1.f - beta) * zc;
        zc = zn;                      // meaningful in lanes 0-7 only
        if (q < 8) z_o[p * 8 + q] = zn;
        if (q == 0) beta_o[p] = beta;
        int t2 = (t + 2 < 512) ? t + 2 : t;
        hp = hid_pre[(size_t)(pbase + t2) * 64 + q];
        if (q < 8) {
            mu = mu_o[(pbase + t2) * 8 + q];
            lv = lv_o[(pbase + t2) * 8 + q];
            ep = eps[(pbase + t2) * 8 + q];
        }
    };

    for (int t = 0; t < 512; t += 2) {
        body(t,     hpa, mua, lva, epa);
        body(t + 1, hpb, mub, lvb, epb);
    }
}

// ---------------------------------------------------------------------------
// Decoder hypernet + rank-R perturbation + LayerNorm + head. P=8/WG.
// ---------------------------------------------------------------------------
__global__ __launch_bounds__(256, 3) void decoder_final(
    const float* __restrict__ e_seq, const float* __restrict__ z_o,
    const float* __restrict__ dec1_w, const float* __restrict__ dec1_b,
    const float* __restrict__ dec2_w, const float* __restrict__ dec2_b,
    const float* __restrict__ ln_g, const float* __restrict__ ln_b,
    const float* __restrict__ head_w, const float* __restrict__ head_b,
    float* __restrict__ logits)
{
    __shared__ __align__(16) float e_l[8][256];
    __shared__ __align__(16) float hmid[8][32];
    __shared__ float zl[8][8];
    __shared__ float tmpw[8][16];
    __shared__ __align__(16) float partb[2048];
    __shared__ float red1[8][16];
    __shared__ float red2[8][16];
    __shared__ float stats[8][2];
    int tid = threadIdx.x;
    int p0 = blockIdx.x * 8;

    {
        const float4* eg = (const float4*)(e_seq + (size_t)p0 * 256);
        float4* el4 = (float4*)&e_l[0][0];
        el4[tid] = eg[tid];
        el4[tid + 256] = eg[tid + 256];
        if (tid < 64) ((float*)zl)[tid] = z_o[p0 * 8 + tid];
    }
    __syncthreads();
    {
        int pp = tid >> 5, g = tid & 31;
        float a = dec1_b[g];
        #pragma unroll
        for (int x = 0; x < 8; ++x) a += dec1_w[g * 8 + x] * zl[pp][x];
        hmid[pp][g] = tanh_(a);
    }
    __syncthreads();
    // ---- pass B: tmp[pp][r] = sum_d Bm[d,r]*e[d]
    {
        int r = tid & 15, dgrp = tid >> 4;
        float acc[8];
        #pragma unroll
        for (int pp = 0; pp < 8; ++pp) acc[pp] = 0.f;
        for (int iblk = 0; iblk < 8; ++iblk) {
            float4 wr[2][8]; float wb[2]; int dd[2];
            #pragma unroll
            for (int ii = 0; ii < 2; ++ii) {
                int d = dgrp + 16 * (iblk * 2 + ii);
                dd[ii] = d;
                int row = 4096 + d * 16 + r;
                const float4* wp = (const float4*)(dec2_w + (size_t)row * 32);
                #pragma unroll
                for (int g = 0; g < 8; ++g) wr[ii][g] = wp[g];
                wb[ii] = dec2_b[row];
            }
            #pragma unroll 1
            for (int pp = 0; pp < 8; ++pp) {
                const float4* hv = (const float4*)hmid[pp];
                float b0 = wb[0], b1 = wb[1];
                #pragma unroll
                for (int g = 0; g < 8; ++g) {
                    float4 hh = hv[g];
                    b0 += dot4(wr[0][g], hh);
                    b1 += dot4(wr[1][g], hh);
                }
                acc[pp] += b0 * e_l[pp][dd[0]] + b1 * e_l[pp][dd[1]];
            }
        }
        #pragma unroll
        for (int pp = 0; pp < 8; ++pp) partb[(pp * 16 + r) * 16 + dgrp] = acc[pp];
    }
    __syncthreads();
    if (tid < 128) {
        int pp = tid >> 4, rr = tid & 15;
        float s = 0.f;
        #pragma unroll
        for (int dg = 0; dg < 16; ++dg) s += partb[(pp * 16 + rr) * 16 + dg];
        tmpw[pp][rr] = s;
    }
    __syncthreads();
    // ---- pass A
    {
        int d = tid;
        float po[8];
        #pragma unroll
        for (int pp = 0; pp < 8; ++pp) po[pp] = e_l[pp][d];
        for (int rblk = 0; rblk < 8; ++rblk) {
            float4 wr[2][8]; float wb[2];
            #pragma unroll
            for (int ii = 0; ii < 2; ++ii) {
                int row = d * 16 + rblk * 2 + ii;
                const float4* wp = (const float4*)(dec2_w + (size_t)row * 32);
                #pragma unroll
                for (int g = 0; g < 8; ++g) wr[ii][g] = wp[g];
                wb[ii] = dec2_b[row];
            }
            #pragma unroll 1
            for (int pp = 0; pp < 8; ++pp) {
                const float4* hv = (const float4*)hmid[pp];
                float a0 = wb[0], a1 = wb[1];
                #pragma unroll
                for (int g = 0; g < 8; ++g) {
                    float4 hh = hv[g];
                    a0 += dot4(wr[0][g], hh);
                    a1 += dot4(wr[1][g], hh);
                }
                po[pp] += a0 * tmpw[pp][rblk * 2] + a1 * tmpw[pp][rblk * 2 + 1];
            }
        }
        #pragma unroll
        for (int pp = 0; pp < 8; ++pp) partb[pp * 256 + d] = po[pp];
    }
    __syncthreads();
    if (tid < 128) {
        int pp = tid >> 4, c = tid & 15;
        float s = 0.f, s2 = 0.f;
        #pragma unroll
        for (int i = 0; i < 16; ++i) { float v = partb[pp * 256 + c * 16 + i]; s += v; s2 += v * v; }
        red1[pp][c] = s; red2[pp][c] = s2;
    }
    __syncthreads();
    if (tid < 8) {
        float s = 0.f, s2 = 0.f;
        #pragma unroll
        for (int c = 0; c < 16; ++c) { s += red1[tid][c]; s2 += red2[tid][c]; }
        float mean = s * (1.f / 256.f);
        float var = s2 * (1.f / 256.f) - mean * mean;
        stats[tid][0] = mean;
        stats[tid][1] = rsqrtf(var + 1e-5f);
    }
    __syncthreads();
    {
        int d = tid;
        float g = ln_g[d], bln = ln_b[d];
        #pragma unroll
        for (int pp = 0; pp < 8; ++pp) {
            float v = (partb[pp * 256 + d] - stats[pp][0]) * stats[pp][1];
            partb[pp * 256 + d] = v * g + bln;
        }
    }
    __syncthreads();
    if (tid < 144) {
        int pp = tid / 18, na = tid - pp * 18;
        float a = head_b[na];
        for (int d2 = 0; d2 < 256; ++d2)
            a += partb[pp * 256 + d2] * head_w[na * 256 + d2];
        logits[(size_t)(p0 + pp) * 18 + na] = a;
    }
}

// ---------------------------------------------------------------------------
extern "C" void kernel_launch(void* const* d_in, const int* in_sizes, int n_in,
                              void* d_out, int out_size, void* d_ws, size_t ws_size,
                              hipStream_t stream) {
    (void)in_sizes; (void)n_in; (void)out_size; (void)ws_size;
    const float* e     = (const float*)d_in[0];
    const float* eps   = (const float*)d_in[1];
    const float* wih_f = (const float*)d_in[2];
    const float* whh_f = (const float*)d_in[3];
    const float* bih_f = (const float*)d_in[4];
    const float* bhh_f = (const float*)d_in[5];
    const float* wih_b = (const float*)d_in[6];
    const float* whh_b = (const float*)d_in[7];
    const float* bih_b = (const float*)d_in[8];
    const float* bhh_b = (const float*)d_in[9];
    const float* wih_e = (const float*)d_in[10];
    const float* whh_e = (const float*)d_in[11];
    const float* bih_e = (const float*)d_in[12];
    const float* bhh_e = (const float*)d_in[13];
    const float* mu_w  = (const float*)d_in[14];
    const float* mu_b  = (const float*)d_in[15];
    const float* lv_w  = (const float*)d_in[16];
    const float* lv_b  = (const float*)d_in[17];
    const float* sw1_w = (const float*)d_in[18];
    const float* sw1_b = (const float*)d_in[19];
    const float* sw2_w = (const float*)d_in[20];
    const float* sw2_b = (const float*)d_in[21];
    const float* dec1_w = (const float*)d_in[22];
    const float* dec1_b = (const float*)d_in[23];
    const float* dec2_w = (const float*)d_in[24];
    const float* dec2_b = (const float*)d_in[25];
    const float* ln_g  = (const float*)d_in[26];
    const float* ln_b  = (const float*)d_in[27];
    const float* head_w = (const float*)d_in[28];
    const float* head_b = (const float*)d_in[29];

    float* ws    = (float*)d_ws;
    float* gi_f  = ws;                       // 8192*384
    float* gi_b  = gi_f + 3145728;           // 8192*384
    float* gie   = gi_b + 3145728;           // 8192*96
    float* swe   = gie + 786432;             // 8192*64 (hid_pre)
    float* s_seq = swe + 524288;             // 8192*256
    float* h_seq = s_seq + 2097152;          // 8192*32
    unsigned* pk   = (unsigned*)(h_seq + 262144);  // 49152 dwords (gru f16 B-frags)
    unsigned* pk_e = pk + 49152;                   // 1536 dwords (ctrl f16 pairs)

    float* out       = (float*)d_out;
    float* out_logit = out;                  // 147456
    float* out_mu    = out + 147456;         // 65536
    float* out_lv    = out + 212992;         // 65536
    float* out_beta  = out + 278528;         // 8192
    float* out_z     = out + 286720;         // 65536

    // pack recurrent weights to f16 (thread/frag-contiguous layouts)
    pack_w<<<198, 256, 0, stream>>>(whh_f, whh_b, whh_e, pk, pk_e);
    // big input projections (must precede GRU)
    gemm_k<<<dim3(128, 12), 256, 0, stream>>>(e, 256, wih_f, 256, bih_f, gi_f, 384, 384, 0);
    gemm_k<<<dim3(128, 12), 256, 0, stream>>>(e, 256, wih_b, 256, bih_b, gi_b, 384, 384, 0);
    // GRU recurrence (MFMA) fused with the independent gie/swe e-projections
    gru_fused<<<672, 512, 0, stream>>>(gi_f, gi_b, pk, bhh_f, bhh_b, s_seq,
                                       e, wih_e, bih_e, gie, sw1_w, sw1_b, swe);
    // add s-part of controller GRU input projection
    gemm_k<<<dim3(128, 3), 256, 0, stream>>>(s_seq, 256, wih_e + 256, 512, nullptr, gie, 96, 96, 1);
    // controller h scan
    ctrl_h_scan<<<16, 128, 0, stream>>>(gie, pk_e, bhh_e, h_seq);
    // fused mu / logvar / switching-unit h-part
    heads_k<<<128, 256, 0, stream>>>(h_seq, mu_w, mu_b, lv_w, lv_b, sw1_w, out_mu, out_lv, swe);
    // beta / z scan
    ctrl_z_scan<<<16, 64, 0, stream>>>(swe, sw1_w, sw2_w, sw2_b, eps, out_mu, out_lv, out_beta, out_z);
    // decoder hypernet + perturbation + LN + head
    decoder_final<<<1024, 256, 0, stream>>>(e, out_z, dec1_w, dec1_b, dec2_w, dec2_b,
                                            ln_g, ln_b, head_w, head_b, out_logit);
}

// Round 11
// 1114.465 us; speedup vs baseline: 1.3336x; 1.0985x over previous
//
#include <hip/hip_runtime.h>

#define TT 512
#define BB 16
#define DD 256
#define HHH 128
#define GG 32
#define ZZ 8
#define RR_ 16
#define NAA 18

typedef _Float16 h2v __attribute__((ext_vector_type(2)));
typedef __attribute__((ext_vector_type(4))) float f4;
typedef __attribute__((ext_vector_type(4))) int i4;

__device__ __forceinline__ float sigmoid_(float x) { return 1.f / (1.f + __expf(-x)); }
__device__ __forceinline__ float tanh_(float x) { float e = __expf(2.f * x); return 1.f - 2.f / (e + 1.f); }
__device__ __forceinline__ float dot4(float4 a, float4 b) {
    return a.x * b.x + a.y * b.y + a.z * b.z + a.w * b.w;
}
__device__ __forceinline__ h2v u2h2(unsigned u) { union { unsigned u; h2v h; } c; c.u = u; return c.h; }

// park a dword in an AGPR / fetch it back (opaque to the register allocator)
#define AGPR_STORE(a, v) asm volatile("v_accvgpr_write_b32 %0, %1" : "=a"(a) : "v"(v))
#define AGPR_LOAD(v, a)  asm volatile("v_accvgpr_read_b32 %0, %1" : "=v"(v) : "a"(a))

// VALU-speed cross-lane add via DPP (compiler handles hazard nops)
template <int CTRL, int RM, int BM, bool BC>
__device__ __forceinline__ float dpp_add_f(float v) {
    return v + __int_as_float(__builtin_amdgcn_update_dpp(0, __float_as_int(v), CTRL, RM, BM, BC));
}
// full-wave sum -> lane 63, then broadcast via readlane (SGPR)
__device__ __forceinline__ float wave_sum_bcast(float p) {
    p = dpp_add_f<0x111, 0xf, 0xf, true>(p);   // row_shr:1
    p = dpp_add_f<0x112, 0xf, 0xf, true>(p);   // row_shr:2
    p = dpp_add_f<0x114, 0xf, 0xf, true>(p);   // row_shr:4
    p = dpp_add_f<0x118, 0xf, 0xf, true>(p);   // row_shr:8  (lane 15 of each row = row sum)
    p = dpp_add_f<0x142, 0xa, 0xf, false>(p);  // row_bcast:15 -> rows 1,3
    p = dpp_add_f<0x143, 0xc, 0xf, false>(p);  // row_bcast:31 -> rows 2,3 (lane 63 = total)
    return __int_as_float(__builtin_amdgcn_readlane(__float_as_int(p), 63));
}
// sum over each aligned quad of lanes (all 4 lanes get the sum)
__device__ __forceinline__ float quad_sum(float v) {
    v = dpp_add_f<0xB1, 0xf, 0xf, true>(v);    // quad_perm [1,0,3,2]
    v = dpp_add_f<0x4E, 0xf, 0xf, true>(v);    // quad_perm [2,3,0,1]
    return v;
}

// ---------------------------------------------------------------------------
// Pack recurrent weights to f16.
// gru pk (MFMA B-frag layout, 49152 dw):
//   i = ((((dir*8+w)*3+T)*4+kt)*64+lane)*4+jd
//   -> half2( W[T*128+16w+(lane&15)][kt*32+(lane>>4)*8+2jd], +1 )
// ctrl pk_e (1536 dw): i -> (s,k,j,m): half2(We[j*32+k][8s+2m], +1)
// ---------------------------------------------------------------------------
__global__ __launch_bounds__(256) void pack_w(
    const float* __restrict__ wf, const float* __restrict__ wb,
    const float* __restrict__ we,
    unsigned* __restrict__ pk, unsigned* __restrict__ pk_e)
{
    int i = blockIdx.x * 256 + threadIdx.x;          // 0 .. 50687
    if (i < 49152) {
        int dir = i / 24576; int r = i % 24576;
        int w = r / 3072;    int r2 = r % 3072;
        int T = r2 / 1024;   int r3 = r2 % 1024;
        int kt = r3 / 256;   int r4 = r3 % 256;
        int lane = r4 / 4;   int jd = r4 % 4;
        const float* wsrc = dir ? wb : wf;
        int row = T * 128 + 16 * w + (lane & 15);
        int k0 = kt * 32 + (lane >> 4) * 8 + 2 * jd;
        union { _Float16 h[2]; unsigned u; } c;
        c.h[0] = (_Float16)wsrc[row * 128 + k0];
        c.h[1] = (_Float16)wsrc[row * 128 + k0 + 1];
        pk[i] = c.u;
    } else if (i < 50688) {
        int ie = i - 49152;
        int s = ie / 384;  int rem = ie % 384;
        int k = rem / 12;  int e = rem % 12;
        int j = e / 4;     int m = e % 4;
        int row = j * 32 + k, k0 = 8 * s + 2 * m;
        union { _Float16 h[2]; unsigned u; } c;
        c.h[0] = (_Float16)we[row * 32 + k0];
        c.h[1] = (_Float16)we[row * 32 + k0 + 1];
        pk_e[ie] = c.u;
    }
}

// ---------------------------------------------------------------------------
// Generic tiled GEMM (256 thr): Out[p][n] (+)= bias[n] + A[p]·W[n]
// ---------------------------------------------------------------------------
__global__ __launch_bounds__(256) void gemm_k(
    const float* __restrict__ A, int K, const float* __restrict__ W, int ldw,
    const float* __restrict__ bias, float* __restrict__ Out, int ldout, int N, int accFlag)
{
    __shared__ float At[64][36];
    __shared__ float Wt[32][36];
    int row0 = blockIdx.x * 64, n0 = blockIdx.y * 32;
    int tid = threadIdx.x;
    int tx = tid & 15, ty = tid >> 4;
    float acc[4][2] = {};
    for (int k0 = 0; k0 < K; k0 += 32) {
        #pragma unroll
        for (int i = 0; i < 8; ++i) {
            int idx = tid + i * 256; int rr = idx >> 5, kk = idx & 31;
            At[rr][kk] = A[(size_t)(row0 + rr) * K + k0 + kk];
        }
        #pragma unroll
        for (int i = 0; i < 4; ++i) {
            int idx = tid + i * 256; int nn = idx >> 5, kk = idx & 31;
            Wt[nn][kk] = (n0 + nn < N) ? W[(size_t)(n0 + nn) * ldw + k0 + kk] : 0.f;
        }
        __syncthreads();
        #pragma unroll
        for (int kk = 0; kk < 32; kk += 4) {
            float4 w0 = *(const float4*)&Wt[tx][kk];
            float4 w1 = *(const float4*)&Wt[tx + 16][kk];
            #pragma unroll
            for (int rr = 0; rr < 4; ++rr) {
                float4 av = *(const float4*)&At[ty * 4 + rr][kk];
                acc[rr][0] += dot4(av, w0);
                acc[rr][1] += dot4(av, w1);
            }
        }
        __syncthreads();
    }
    #pragma unroll
    for (int cc = 0; cc < 2; ++cc) {
        int n = n0 + tx + cc * 16;
        if (n < N) {
            float badd = bias ? bias[n] : 0.f;
            #pragma unroll
            for (int rr = 0; rr < 4; ++rr) {
                int row = row0 + ty * 4 + rr;
                float v = acc[rr][cc] + badd;
                if (accFlag) Out[(size_t)row * ldout + n] += v;
                else         Out[(size_t)row * ldout + n] = v;
            }
        }
    }
}

// ---------------------------------------------------------------------------
// Fused dispatch: blocks 0-31 = GRU recurrence via MFMA (AGPR-resident
// B-frags, one barrier/step); blocks 32-415 = gie e-projection; blocks
// 416-671 = swe e-projection (riders on idle CUs).
// ---------------------------------------------------------------------------
struct __align__(16) SmGru { _Float16 hb[2][128]; };
struct __align__(16) SmGemm { float At[64][36]; float Wt[32][36]; };
union __align__(16) SmU { SmGru g; SmGemm m; };

__device__ __forceinline__ void gemm_tile512(
    const float* __restrict__ A, int K, const float* __restrict__ W, int ldw,
    const float* __restrict__ bias, float* __restrict__ Out, int ldout, int N,
    int row0, int n0, SmGemm& sm)
{
    int tid = threadIdx.x;
    int tx = tid & 31, ty = tid >> 5;    // 32 cols x 16 row-groups (4 rows each)
    float acc[4] = {};
    for (int k0 = 0; k0 < K; k0 += 32) {
        #pragma unroll
        for (int i = 0; i < 4; ++i) {
            int idx = tid + i * 512; int rr = idx >> 5, kk = idx & 31;
            sm.At[rr][kk] = A[(size_t)(row0 + rr) * K + k0 + kk];
        }
        #pragma unroll
        for (int i = 0; i < 2; ++i) {
            int idx = tid + i * 512; int nn = idx >> 5, kk = idx & 31;
            sm.Wt[nn][kk] = (n0 + nn < N) ? W[(size_t)(n0 + nn) * ldw + k0 + kk] : 0.f;
        }
        __syncthreads();
        #pragma unroll
        for (int kk = 0; kk < 32; kk += 4) {
            float4 w0 = *(const float4*)&sm.Wt[tx][kk];
            #pragma unroll
            for (int rr = 0; rr < 4; ++rr) {
                float4 av = *(const float4*)&sm.At[ty * 4 + rr][kk];
                acc[rr] += dot4(av, w0);
            }
        }
        __syncthreads();
    }
    int n = n0 + tx;
    if (n < N) {
        float badd = bias ? bias[n] : 0.f;
        #pragma unroll
        for (int rr = 0; rr < 4; ++rr)
            Out[(size_t)(row0 + ty * 4 + rr) * ldout + n] = acc[rr] + badd;
    }
}

__global__ __launch_bounds__(512, 2) void gru_fused(
    const float* __restrict__ gi_f, const float* __restrict__ gi_b,
    const unsigned* __restrict__ pk,
    const float* __restrict__ bhh_f, const float* __restrict__ bhh_b,
    float* __restrict__ s_seq,
    const float* __restrict__ e,
    const float* __restrict__ wih_e, const float* __restrict__ bih_e, float* __restrict__ gie,
    const float* __restrict__ sw1_w, const float* __restrict__ sw1_b, float* __restrict__ swe)
{
    __shared__ SmU sm;
    int bx = blockIdx.x;
    if (bx >= 416) {                 // swe e-part: 8192x64, K=256
        int t = bx - 416;
        gemm_tile512(e, 256, sw1_w, 296, sw1_b, swe, 64, 64, (t & 127) * 64, (t >> 7) * 32, sm.m);
        return;
    }
    if (bx >= 32) {                  // gie e-part: 8192x96, K=256
        int t = bx - 32;
        gemm_tile512(e, 256, wih_e, 512, bih_e, gie, 96, 96, (t & 127) * 64, (t >> 7) * 32, sm.m);
        return;
    }

    // ---------------- GRU (MFMA body) ----------------
    int dir = bx >> 4, b = bx & 15;
    const float* gi  = dir ? gi_b  : gi_f;
    const float* bhh = dir ? bhh_b : bhh_f;
    int tid = threadIdx.x;
    int w = tid >> 6;            // wave 0..7
    int lane = tid & 63;
    int quad = lane >> 4;
    int c = lane & 15;
    int j = 16 * w + c;          // hidden unit for gate lanes (lane < 16)

    // B-fragments: 12 x 4 dwords, permanently AGPR-resident
    i4 bf[3][4];
    #pragma unroll
    for (int T = 0; T < 3; ++T)
        #pragma unroll
        for (int kt = 0; kt < 4; ++kt)
            bf[T][kt] = *(const i4*)(pk + (size_t)((((dir * 8 + w) * 3 + T) * 4 + kt) * 64 + lane) * 4);
    #pragma unroll
    for (int T = 0; T < 3; ++T)
        #pragma unroll
        for (int kt = 0; kt < 4; ++kt)
            asm volatile("" : "+a"(bf[T][kt]));

    if (tid < 128) sm.g.hb[0][tid] = (_Float16)0.f;

    float bhr = 0.f, bhz = 0.f, bhn = 0.f;
    float gra = 0.f, gza = 0.f, gna = 0.f;
    float grb = 0.f, gzb = 0.f, gnb = 0.f;
    float hreg = 0.f;
    if (lane < 16) {
        bhr = bhh[j]; bhz = bhh[128 + j]; bhn = bhh[256 + j];
        int t0 = dir ? 511 : 0;
        int t1 = dir ? 510 : 1;
        size_t p0 = (size_t)(b * TT + t0) * 384;
        size_t p1 = (size_t)(b * TT + t1) * 384;
        gra = gi[p0 + j]; gza = gi[p0 + 128 + j]; gna = gi[p0 + 256 + j];
        grb = gi[p1 + j]; gzb = gi[p1 + 128 + j]; gnb = gi[p1 + 256 + j];
    }
    __syncthreads();

    int cur = 0;
    auto body = [&](int step, float& gr, float& gz, float& gn) {
        // A-fragment: per-quad 16B broadcast of h (all 16 rows = copies of h)
        i4 af[4];
        #pragma unroll
        for (int kt = 0; kt < 4; ++kt)
            af[kt] = *(const i4*)(&sm.g.hb[cur][kt * 32 + quad * 8]);
        f4 accr = {0.f, 0.f, 0.f, 0.f};
        f4 accz = {0.f, 0.f, 0.f, 0.f};
        f4 accn = {0.f, 0.f, 0.f, 0.f};
        asm volatile("s_nop 3");
        #pragma unroll
        for (int kt = 0; kt < 4; ++kt) {
            asm volatile("v_mfma_f32_16x16x32_f16 %0, %1, %2, %0" : "+v"(accr) : "v"(af[kt]), "a"(bf[0][kt]));
            asm volatile("v_mfma_f32_16x16x32_f16 %0, %1, %2, %0" : "+v"(accz) : "v"(af[kt]), "a"(bf[1][kt]));
            asm volatile("v_mfma_f32_16x16x32_f16 %0, %1, %2, %0" : "+v"(accn) : "v"(af[kt]), "a"(bf[2][kt]));
        }
        asm volatile("s_nop 7\n\ts_nop 7");
        if (lane < 16) {
            int t = dir ? (511 - step) : step;
            int p = b * TT + t;
            float r = sigmoid_(gr + bhr + accr[0]);
            float z = sigmoid_(gz + bhz + accz[0]);
            float n = tanh_(gn + r * (bhn + accn[0]));
            float hn = (1.f - z) * n + z * hreg;
            hreg = hn;
            sm.g.hb[cur ^ 1][j] = (_Float16)hn;
            s_seq[(size_t)p * 256 + dir * 128 + j] = hn;
            int s2 = step + 2;
            int tp = (s2 < 512) ? (dir ? (511 - s2) : s2) : t;
            size_t p2 = (size_t)(b * TT + tp) * 384;
            gr = gi[p2 + j]; gz = gi[p2 + 128 + j]; gn = gi[p2 + 256 + j];
        }
        __syncthreads();
        cur ^= 1;
    };

    for (int step = 0; step < 512; step += 2) {
        body(step,     gra, gza, gna);
        body(step + 1, grb, gzb, gnb);
    }
}

// ---------------------------------------------------------------------------
// Fused post-scan heads: mu (8), lv (8), sw1 h-part (64, accumulate).
// ---------------------------------------------------------------------------
__global__ __launch_bounds__(256) void heads_k(
    const float* __restrict__ h_seq,
    const float* __restrict__ mu_w, const float* __restrict__ mu_b,
    const float* __restrict__ lv_w, const float* __restrict__ lv_b,
    const float* __restrict__ sw1_w,
    float* __restrict__ out_mu, float* __restrict__ out_lv, float* __restrict__ swe)
{
    __shared__ __align__(16) float Ah[64][32];
    int row0 = blockIdx.x * 64;
    int tid = threadIdx.x;
    #pragma unroll
    for (int i = 0; i < 8; ++i) {
        int idx = tid + i * 256; int rr = idx >> 5, kk = idx & 31;
        Ah[rr][kk] = h_seq[(size_t)(row0 + rr) * 32 + kk];
    }
    __syncthreads();
    int r = tid >> 2, g = tid & 3;
    const float4* av = (const float4*)Ah[r];
    float4 a[8];
    #pragma unroll
    for (int i = 0; i < 8; ++i) a[i] = av[i];
    int row = row0 + r;
    for (int c = 0; c < 20; ++c) {
        int n = g * 20 + c;
        const float* wrow;
        if (n < 8)       wrow = mu_w + n * 32;
        else if (n < 16) wrow = lv_w + (n - 8) * 32;
        else             wrow = sw1_w + (size_t)(n - 16) * 296 + 256;
        const float4* wv = (const float4*)wrow;
        float acc = 0.f;
        #pragma unroll
        for (int i = 0; i < 8; ++i) acc += dot4(wv[i], a[i]);
        if (n < 8)       out_mu[row * 8 + n] = acc + mu_b[n];
        else if (n < 16) out_lv[row * 8 + (n - 8)] = acc + lv_b[n - 8];
        else             swe[(size_t)row * 64 + (n - 16)] += acc;
    }
}

// ---------------------------------------------------------------------------
// Controller h-scan. 16 WGs, 128 threads (2 waves). Single-barrier
// structure, quad_perm DPP reduce (VALU-speed, replaces ds_bpermute shfls).
// ---------------------------------------------------------------------------
__global__ __launch_bounds__(128, 1) void ctrl_h_scan(
    const float* __restrict__ gie, const unsigned* __restrict__ pk_e,
    const float* __restrict__ bhh_e, float* __restrict__ h_seq)
{
    int b = blockIdx.x, tid = threadIdx.x;
    int k = tid >> 2;            // hidden unit 0..31
    int s = tid & 3;             // slice 0..3 (8 h-values each)

    unsigned ag[12];
    {
        const uint4* wp = (const uint4*)(pk_e + ((size_t)(s * 32) + k) * 12);
        #pragma unroll
        for (int i = 0; i < 3; ++i) {
            uint4 u = wp[i];
            AGPR_STORE(ag[4 * i + 0], u.x);
            AGPR_STORE(ag[4 * i + 1], u.y);
            AGPR_STORE(ag[4 * i + 2], u.z);
            AGPR_STORE(ag[4 * i + 3], u.w);
        }
    }

    __shared__ __align__(16) _Float16 hb[2][32];
    if (tid < 32) hb[0][tid] = (_Float16)0.f;

    int pbase = b * TT;
    float bhr = 0.f, bhz = 0.f, bhn = 0.f;
    float g1a = 0.f, g2a = 0.f, g3a = 0.f, g1b = 0.f, g2b = 0.f, g3b = 0.f;
    float hreg = 0.f;
    if (s == 0) {
        bhr = bhh_e[k]; bhz = bhh_e[32 + k]; bhn = bhh_e[64 + k];
        size_t p0 = (size_t)pbase * 96, p1 = (size_t)(pbase + 1) * 96;
        g1a = gie[p0 + k]; g2a = gie[p0 + 32 + k]; g3a = gie[p0 + 64 + k];
        g1b = gie[p1 + k]; g2b = gie[p1 + 32 + k]; g3b = gie[p1 + 64 + k];
    }
    __syncthreads();

    int cur = 0;
    auto body = [&](int t, float& g1, float& g2, float& g3) {
        const uint4* hv = (const uint4*)(&hb[cur][0]) + s;
        uint4 h4 = hv[0];
        unsigned hw[4] = { h4.x, h4.y, h4.z, h4.w };
        float a0 = 0.f, a1 = 0.f, a2 = 0.f;
        #pragma unroll
        for (int m = 0; m < 4; ++m) {
            unsigned w0, w1, w2;
            AGPR_LOAD(w0, ag[m]);
            AGPR_LOAD(w1, ag[4 + m]);
            AGPR_LOAD(w2, ag[8 + m]);
            h2v hh = u2h2(hw[m]);
            a0 = __builtin_amdgcn_fdot2(u2h2(w0), hh, a0, false);
            a1 = __builtin_amdgcn_fdot2(u2h2(w1), hh, a1, false);
            a2 = __builtin_amdgcn_fdot2(u2h2(w2), hh, a2, false);
        }
        a0 = quad_sum(a0);
        a1 = quad_sum(a1);
        a2 = quad_sum(a2);

        if (s == 0) {
            float r = sigmoid_(g1 + bhr + a0);
            float z = sigmoid_(g2 + bhz + a1);
            float n = tanh_(g3 + r * (bhn + a2));
            float hn = (1.f - z) * n + z * hreg;
            hreg = hn;
            hb[cur ^ 1][k] = (_Float16)hn;
            h_seq[(size_t)(pbase + t) * 32 + k] = hn;
            int t2 = (t + 2 < 512) ? t + 2 : t;
            size_t p2 = (size_t)(pbase + t2) * 96;
            g1 = gie[p2 + k]; g2 = gie[p2 + 32 + k]; g3 = gie[p2 + 64 + k];
        }
        __syncthreads();
        cur ^= 1;
    };

    for (int t = 0; t < 512; t += 2) {
        body(t,     g1a, g2a, g3a);
        body(t + 1, g1b, g2b, g3b);
    }
}

// ---------------------------------------------------------------------------
// Controller z/beta scan. 16 WGs, 1 wave, no LDS, no barriers, NO bpermute:
// all 8 z live in every lane's registers; cand = mu+exp(0.5lv)*eps is
// z-independent -> precomputed in the prefetch (off the chain); the 64-lane
// dot reduce is a VALU-speed DPP ladder + readlane (SGPR-uniform beta).
// R10's 304us was 6x ds_bpermute (~120cy each) on the step chain.
// ---------------------------------------------------------------------------
__global__ __launch_bounds__(64, 1) void ctrl_z_scan(
    const float* __restrict__ hid_pre, const float* __restrict__ sw1_w,
    const float* __restrict__ sw2_w, const float* __restrict__ sw2_b,
    const float* __restrict__ eps, const float* __restrict__ mu_o,
    const float* __restrict__ lv_o, float* __restrict__ beta_o, float* __restrict__ z_o)
{
    int b = blockIdx.x, q = threadIdx.x;
    float wz[8];
    #pragma unroll
    for (int x = 0; x < 8; ++x) wz[x] = sw1_w[(size_t)q * 296 + 288 + x];
    float w2 = sw2_w[q];
    float bb = sw2_b[0];
    float4 z03 = {0.f, 0.f, 0.f, 0.f}, z47 = {0.f, 0.f, 0.f, 0.f};
    int pbase = b * TT;

    auto loadcand = [&](int p, float4& c03, float4& c47) {
        float4 m0 = *(const float4*)(mu_o + p * 8);
        float4 m1 = *(const float4*)(mu_o + p * 8 + 4);
        float4 l0 = *(const float4*)(lv_o + p * 8);
        float4 l1 = *(const float4*)(lv_o + p * 8 + 4);
        float4 e0 = *(const float4*)(eps + p * 8);
        float4 e1 = *(const float4*)(eps + p * 8 + 4);
        c03 = make_float4(m0.x + __expf(0.5f * l0.x) * e0.x, m0.y + __expf(0.5f * l0.y) * e0.y,
                          m0.z + __expf(0.5f * l0.z) * e0.z, m0.w + __expf(0.5f * l0.w) * e0.w);
        c47 = make_float4(m1.x + __expf(0.5f * l1.x) * e1.x, m1.y + __expf(0.5f * l1.y) * e1.y,
                          m1.z + __expf(0.5f * l1.z) * e1.z, m1.w + __expf(0.5f * l1.w) * e1.w);
    };

    float hpa = hid_pre[(size_t)pbase * 64 + q];
    float hpb = hid_pre[(size_t)(pbase + 1) * 64 + q];
    float4 c03a, c47a, c03b, c47b;
    loadcand(pbase, c03a, c47a);
    loadcand(pbase + 1, c03b, c47b);

    auto body = [&](int t, float& hp, float4& c03, float4& c47) {
        int p = pbase + t;
        float a = hp
            + wz[0] * z03.x + wz[1] * z03.y + wz[2] * z03.z + wz[3] * z03.w
            + wz[4] * z47.x + wz[5] * z47.y + wz[6] * z47.z + wz[7] * z47.w;
        float hid = tanh_(a);
        float total = wave_sum_bcast(w2 * hid);
        float beta = sigmoid_(total + bb);
        float omb = 1.f - beta;
        z03.x = beta * c03.x + omb * z03.x;  z03.y = beta * c03.y + omb * z03.y;
        z03.z = beta * c03.z + omb * z03.z;  z03.w = beta * c03.w + omb * z03.w;
        z47.x = beta * c47.x + omb * z47.x;  z47.y = beta * c47.y + omb * z47.y;
        z47.z = beta * c47.z + omb * z47.z;  z47.w = beta * c47.w + omb * z47.w;
        if (q == 0) {
            *(float4*)(z_o + p * 8) = z03;
            *(float4*)(z_o + p * 8 + 4) = z47;
            beta_o[p] = beta;
        }
        int t2 = (t + 2 < 512) ? t + 2 : t;
        hp = hid_pre[(size_t)(pbase + t2) * 64 + q];
        loadcand(pbase + t2, c03, c47);
    };

    for (int t = 0; t < 512; t += 2) {
        body(t,     hpa, c03a, c47a);
        body(t + 1, hpb, c03b, c47b);
    }
}

// ---------------------------------------------------------------------------
// Decoder hypernet + rank-R perturbation + LayerNorm + head. P=8/WG.
// ---------------------------------------------------------------------------
__global__ __launch_bounds__(256, 3) void decoder_final(
    const float* __restrict__ e_seq, const float* __restrict__ z_o,
    const float* __restrict__ dec1_w, const float* __restrict__ dec1_b,
    const float* __restrict__ dec2_w, const float* __restrict__ dec2_b,
    const float* __restrict__ ln_g, const float* __restrict__ ln_b,
    const float* __restrict__ head_w, const float* __restrict__ head_b,
    float* __restrict__ logits)
{
    __shared__ __align__(16) float e_l[8][256];
    __shared__ __align__(16) float hmid[8][32];
    __shared__ float zl[8][8];
    __shared__ float tmpw[8][16];
    __shared__ __align__(16) float partb[2048];
    __shared__ float red1[8][16];
    __shared__ float red2[8][16];
    __shared__ float stats[8][2];
    int tid = threadIdx.x;
    int p0 = blockIdx.x * 8;

    {
        const float4* eg = (const float4*)(e_seq + (size_t)p0 * 256);
        float4* el4 = (float4*)&e_l[0][0];
        el4[tid] = eg[tid];
        el4[tid + 256] = eg[tid + 256];
        if (tid < 64) ((float*)zl)[tid] = z_o[p0 * 8 + tid];
    }
    __syncthreads();
    {
        int pp = tid >> 5, g = tid & 31;
        float a = dec1_b[g];
        #pragma unroll
        for (int x = 0; x < 8; ++x) a += dec1_w[g * 8 + x] * zl[pp][x];
        hmid[pp][g] = tanh_(a);
    }
    __syncthreads();
    // ---- pass B: tmp[pp][r] = sum_d Bm[d,r]*e[d]
    {
        int r = tid & 15, dgrp = tid >> 4;
        float acc[8];
        #pragma unroll
        for (int pp = 0; pp < 8; ++pp) acc[pp] = 0.f;
        for (int iblk = 0; iblk < 8; ++iblk) {
            float4 wr[2][8]; float wb[2]; int dd[2];
            #pragma unroll
            for (int ii = 0; ii < 2; ++ii) {
                int d = dgrp + 16 * (iblk * 2 + ii);
                dd[ii] = d;
                int row = 4096 + d * 16 + r;
                const float4* wp = (const float4*)(dec2_w + (size_t)row * 32);
                #pragma unroll
                for (int g = 0; g < 8; ++g) wr[ii][g] = wp[g];
                wb[ii] = dec2_b[row];
            }
            #pragma unroll 1
            for (int pp = 0; pp < 8; ++pp) {
                const float4* hv = (const float4*)hmid[pp];
                float b0 = wb[0], b1 = wb[1];
                #pragma unroll
                for (int g = 0; g < 8; ++g) {
                    float4 hh = hv[g];
                    b0 += dot4(wr[0][g], hh);
                    b1 += dot4(wr[1][g], hh);
                }
                acc[pp] += b0 * e_l[pp][dd[0]] + b1 * e_l[pp][dd[1]];
            }
        }
        #pragma unroll
        for (int pp = 0; pp < 8; ++pp) partb[(pp * 16 + r) * 16 + dgrp] = acc[pp];
    }
    __syncthreads();
    if (tid < 128) {
        int pp = tid >> 4, rr = tid & 15;
        float s = 0.f;
        #pragma unroll
        for (int dg = 0; dg < 16; ++dg) s += partb[(pp * 16 + rr) * 16 + dg];
        tmpw[pp][rr] = s;
    }
    __syncthreads();
    // ---- pass A
    {
        int d = tid;
        float po[8];
        #pragma unroll
        for (int pp = 0; pp < 8; ++pp) po[pp] = e_l[pp][d];
        for (int rblk = 0; rblk < 8; ++rblk) {
            float4 wr[2][8]; float wb[2];
            #pragma unroll
            for (int ii = 0; ii < 2; ++ii) {
                int row = d * 16 + rblk * 2 + ii;
                const float4* wp = (const float4*)(dec2_w + (size_t)row * 32);
                #pragma unroll
                for (int g = 0; g < 8; ++g) wr[ii][g] = wp[g];
                wb[ii] = dec2_b[row];
            }
            #pragma unroll 1
            for (int pp = 0; pp < 8; ++pp) {
                const float4* hv = (const float4*)hmid[pp];
                float a0 = wb[0], a1 = wb[1];
                #pragma unroll
                for (int g = 0; g < 8; ++g) {
                    float4 hh = hv[g];
                    a0 += dot4(wr[0][g], hh);
                    a1 += dot4(wr[1][g], hh);
                }
                po[pp] += a0 * tmpw[pp][rblk * 2] + a1 * tmpw[pp][rblk * 2 + 1];
            }
        }
        #pragma unroll
        for (int pp = 0; pp < 8; ++pp) partb[pp * 256 + d] = po[pp];
    }
    __syncthreads();
    if (tid < 128) {
        int pp = tid >> 4, c = tid & 15;
        float s = 0.f, s2 = 0.f;
        #pragma unroll
        for (int i = 0; i < 16; ++i) { float v = partb[pp * 256 + c * 16 + i]; s += v; s2 += v * v; }
        red1[pp][c] = s; red2[pp][c] = s2;
    }
    __syncthreads();
    if (tid < 8) {
        float s = 0.f, s2 = 0.f;
        #pragma unroll
        for (int c = 0; c < 16; ++c) { s += red1[tid][c]; s2 += red2[tid][c]; }
        float mean = s * (1.f / 256.f);
        float var = s2 * (1.f / 256.f) - mean * mean;
        stats[tid][0] = mean;
        stats[tid][1] = rsqrtf(var + 1e-5f);
    }
    __syncthreads();
    {
        int d = tid;
        float g = ln_g[d], bln = ln_b[d];
        #pragma unroll
        for (int pp = 0; pp < 8; ++pp) {
            float v = (partb[pp * 256 + d] - stats[pp][0]) * stats[pp][1];
            partb[pp * 256 + d] = v * g + bln;
        }
    }
    __syncthreads();
    if (tid < 144) {
        int pp = tid / 18, na = tid - pp * 18;
        float a = head_b[na];
        for (int d2 = 0; d2 < 256; ++d2)
            a += partb[pp * 256 + d2] * head_w[na * 256 + d2];
        logits[(size_t)(p0 + pp) * 18 + na] = a;
    }
}

// ---------------------------------------------------------------------------
extern "C" void kernel_launch(void* const* d_in, const int* in_sizes, int n_in,
                              void* d_out, int out_size, void* d_ws, size_t ws_size,
                              hipStream_t stream) {
    (void)in_sizes; (void)n_in; (void)out_size; (void)ws_size;
    const float* e     = (const float*)d_in[0];
    const float* eps   = (const float*)d_in[1];
    const float* wih_f = (const float*)d_in[2];
    const float* whh_f = (const float*)d_in[3];
    const float* bih_f = (const float*)d_in[4];
    const float* bhh_f = (const float*)d_in[5];
    const float* wih_b = (const float*)d_in[6];
    const float* whh_b = (const float*)d_in[7];
    const float* bih_b = (const float*)d_in[8];
    const float* bhh_b = (const float*)d_in[9];
    const float* wih_e = (const float*)d_in[10];
    const float* whh_e = (const float*)d_in[11];
    const float* bih_e = (const float*)d_in[12];
    const float* bhh_e = (const float*)d_in[13];
    const float* mu_w  = (const float*)d_in[14];
    const float* mu_b  = (const float*)d_in[15];
    const float* lv_w  = (const float*)d_in[16];
    const float* lv_b  = (const float*)d_in[17];
    const float* sw1_w = (const float*)d_in[18];
    const float* sw1_b = (const float*)d_in[19];
    const float* sw2_w = (const float*)d_in[20];
    const float* sw2_b = (const float*)d_in[21];
    const float* dec1_w = (const float*)d_in[22];
    const float* dec1_b = (const float*)d_in[23];
    const float* dec2_w = (const float*)d_in[24];
    const float* dec2_b = (const float*)d_in[25];
    const float* ln_g  = (const float*)d_in[26];
    const float* ln_b  = (const float*)d_in[27];
    const float* head_w = (const float*)d_in[28];
    const float* head_b = (const float*)d_in[29];

    float* ws    = (float*)d_ws;
    float* gi_f  = ws;                       // 8192*384
    float* gi_b  = gi_f + 3145728;           // 8192*384
    float* gie   = gi_b + 3145728;           // 8192*96
    float* swe   = gie + 786432;             // 8192*64 (hid_pre)
    float* s_seq = swe + 524288;             // 8192*256
    float* h_seq = s_seq + 2097152;          // 8192*32
    unsigned* pk   = (unsigned*)(h_seq + 262144);  // 49152 dwords (gru f16 B-frags)
    unsigned* pk_e = pk + 49152;                   // 1536 dwords (ctrl f16 pairs)

    float* out       = (float*)d_out;
    float* out_logit = out;                  // 147456
    float* out_mu    = out + 147456;         // 65536
    float* out_lv    = out + 212992;         // 65536
    float* out_beta  = out + 278528;         // 8192
    float* out_z     = out + 286720;         // 65536

    // pack recurrent weights to f16 (thread/frag-contiguous layouts)
    pack_w<<<198, 256, 0, stream>>>(whh_f, whh_b, whh_e, pk, pk_e);
    // big input projections (must precede GRU)
    gemm_k<<<dim3(128, 12), 256, 0, stream>>>(e, 256, wih_f, 256, bih_f, gi_f, 384, 384, 0);
    gemm_k<<<dim3(128, 12), 256, 0, stream>>>(e, 256, wih_b, 256, bih_b, gi_b, 384, 384, 0);
    // GRU recurrence (MFMA) fused with the independent gie/swe e-projections
    gru_fused<<<672, 512, 0, stream>>>(gi_f, gi_b, pk, bhh_f, bhh_b, s_seq,
                                       e, wih_e, bih_e, gie, sw1_w, sw1_b, swe);
    // add s-part of controller GRU input projection
    gemm_k<<<dim3(128, 3), 256, 0, stream>>>(s_seq, 256, wih_e + 256, 512, nullptr, gie, 96, 96, 1);
    // controller h scan
    ctrl_h_scan<<<16, 128, 0, stream>>>(gie, pk_e, bhh_e, h_seq);
    // fused mu / logvar / switching-unit h-part
    heads_k<<<128, 256, 0, stream>>>(h_seq, mu_w, mu_b, lv_w, lv_b, sw1_w, out_mu, out_lv, swe);
    // beta / z scan
    ctrl_z_scan<<<16, 64, 0, stream>>>(swe, sw1_w, sw2_w, sw2_b, eps, out_mu, out_lv, out_beta, out_z);
    // decoder hypernet + perturbation + LN + head
    decoder_final<<<1024, 256, 0, stream>>>(e, out_z, dec1_w, dec1_b, dec2_w, dec2_b,
                                            ln_g, ln_b, head_w, head_b, out_logit);
}

// Round 12
// 1086.811 us; speedup vs baseline: 1.3675x; 1.0254x over previous
//
#include <hip/hip_runtime.h>

#define TT 512
#define BB 16
#define DD 256
#define HHH 128
#define GG 32
#define ZZ 8
#define RR_ 16
#define NAA 18

typedef _Float16 h2v __attribute__((ext_vector_type(2)));
typedef __attribute__((ext_vector_type(4))) float f4;
typedef __attribute__((ext_vector_type(4))) int i4;

__device__ __forceinline__ float sigmoid_(float x) { return 1.f / (1.f + __expf(-x)); }
__device__ __forceinline__ float tanh_(float x) { float e = __expf(2.f * x); return 1.f - 2.f / (e + 1.f); }
__device__ __forceinline__ float dot4(float4 a, float4 b) {
    return a.x * b.x + a.y * b.y + a.z * b.z + a.w * b.w;
}
__device__ __forceinline__ h2v u2h2(unsigned u) { union { unsigned u; h2v h; } c; c.u = u; return c.h; }

// Workgroup barrier WITHOUT the vmcnt(0) drain __syncthreads carries.
// Safe when cross-wave data flows through LDS only: global stores retire in
// the background, prefetch loads keep their compiler-tracked vmcnt slack.
__device__ __forceinline__ void lds_barrier() {
    asm volatile("s_waitcnt lgkmcnt(0)" ::: "memory");
    __builtin_amdgcn_s_barrier();
}

// park a dword in an AGPR / fetch it back (opaque to the register allocator)
#define AGPR_STORE(a, v) asm volatile("v_accvgpr_write_b32 %0, %1" : "=a"(a) : "v"(v))
#define AGPR_LOAD(v, a)  asm volatile("v_accvgpr_read_b32 %0, %1" : "=v"(v) : "a"(a))

// VALU-speed cross-lane add via DPP
template <int CTRL, int RM, int BM, bool BC>
__device__ __forceinline__ float dpp_add_f(float v) {
    return v + __int_as_float(__builtin_amdgcn_update_dpp(0, __float_as_int(v), CTRL, RM, BM, BC));
}
__device__ __forceinline__ float wave_sum_bcast(float p) {
    p = dpp_add_f<0x111, 0xf, 0xf, true>(p);
    p = dpp_add_f<0x112, 0xf, 0xf, true>(p);
    p = dpp_add_f<0x114, 0xf, 0xf, true>(p);
    p = dpp_add_f<0x118, 0xf, 0xf, true>(p);
    p = dpp_add_f<0x142, 0xa, 0xf, false>(p);
    p = dpp_add_f<0x143, 0xc, 0xf, false>(p);
    return __int_as_float(__builtin_amdgcn_readlane(__float_as_int(p), 63));
}
__device__ __forceinline__ float quad_sum(float v) {
    v = dpp_add_f<0xB1, 0xf, 0xf, true>(v);
    v = dpp_add_f<0x4E, 0xf, 0xf, true>(v);
    return v;
}

// ---------------------------------------------------------------------------
// Pack recurrent weights to f16 (layouts unchanged from R10/R11).
// ---------------------------------------------------------------------------
__global__ __launch_bounds__(256) void pack_w(
    const float* __restrict__ wf, const float* __restrict__ wb,
    const float* __restrict__ we,
    unsigned* __restrict__ pk, unsigned* __restrict__ pk_e)
{
    int i = blockIdx.x * 256 + threadIdx.x;          // 0 .. 50687
    if (i < 49152) {
        int dir = i / 24576; int r = i % 24576;
        int w = r / 3072;    int r2 = r % 3072;
        int T = r2 / 1024;   int r3 = r2 % 1024;
        int kt = r3 / 256;   int r4 = r3 % 256;
        int lane = r4 / 4;   int jd = r4 % 4;
        const float* wsrc = dir ? wb : wf;
        int row = T * 128 + 16 * w + (lane & 15);
        int k0 = kt * 32 + (lane >> 4) * 8 + 2 * jd;
        union { _Float16 h[2]; unsigned u; } c;
        c.h[0] = (_Float16)wsrc[row * 128 + k0];
        c.h[1] = (_Float16)wsrc[row * 128 + k0 + 1];
        pk[i] = c.u;
    } else if (i < 50688) {
        int ie = i - 49152;
        int s = ie / 384;  int rem = ie % 384;
        int k = rem / 12;  int e = rem % 12;
        int j = e / 4;     int m = e % 4;
        int row = j * 32 + k, k0 = 8 * s + 2 * m;
        union { _Float16 h[2]; unsigned u; } c;
        c.h[0] = (_Float16)we[row * 32 + k0];
        c.h[1] = (_Float16)we[row * 32 + k0 + 1];
        pk_e[ie] = c.u;
    }
}

// ---------------------------------------------------------------------------
// Generic tiled GEMM (256 thr): Out[p][n] (+)= bias[n] + A[p]·W[n]
// ---------------------------------------------------------------------------
__global__ __launch_bounds__(256) void gemm_k(
    const float* __restrict__ A, int K, const float* __restrict__ W, int ldw,
    const float* __restrict__ bias, float* __restrict__ Out, int ldout, int N, int accFlag)
{
    __shared__ float At[64][36];
    __shared__ float Wt[32][36];
    int row0 = blockIdx.x * 64, n0 = blockIdx.y * 32;
    int tid = threadIdx.x;
    int tx = tid & 15, ty = tid >> 4;
    float acc[4][2] = {};
    for (int k0 = 0; k0 < K; k0 += 32) {
        #pragma unroll
        for (int i = 0; i < 8; ++i) {
            int idx = tid + i * 256; int rr = idx >> 5, kk = idx & 31;
            At[rr][kk] = A[(size_t)(row0 + rr) * K + k0 + kk];
        }
        #pragma unroll
        for (int i = 0; i < 4; ++i) {
            int idx = tid + i * 256; int nn = idx >> 5, kk = idx & 31;
            Wt[nn][kk] = (n0 + nn < N) ? W[(size_t)(n0 + nn) * ldw + k0 + kk] : 0.f;
        }
        __syncthreads();
        #pragma unroll
        for (int kk = 0; kk < 32; kk += 4) {
            float4 w0 = *(const float4*)&Wt[tx][kk];
            float4 w1 = *(const float4*)&Wt[tx + 16][kk];
            #pragma unroll
            for (int rr = 0; rr < 4; ++rr) {
                float4 av = *(const float4*)&At[ty * 4 + rr][kk];
                acc[rr][0] += dot4(av, w0);
                acc[rr][1] += dot4(av, w1);
            }
        }
        __syncthreads();
    }
    #pragma unroll
    for (int cc = 0; cc < 2; ++cc) {
        int n = n0 + tx + cc * 16;
        if (n < N) {
            float badd = bias ? bias[n] : 0.f;
            #pragma unroll
            for (int rr = 0; rr < 4; ++rr) {
                int row = row0 + ty * 4 + rr;
                float v = acc[rr][cc] + badd;
                if (accFlag) Out[(size_t)row * ldout + n] += v;
                else         Out[(size_t)row * ldout + n] = v;
            }
        }
    }
}

// ---------------------------------------------------------------------------
// Both gi projections (fwd+bwd) in ONE launch: grid (128, 24); y<12 -> fwd.
// ---------------------------------------------------------------------------
__global__ __launch_bounds__(256) void gemm_gi(
    const float* __restrict__ A,
    const float* __restrict__ wf, const float* __restrict__ bf, float* __restrict__ of,
    const float* __restrict__ wb, const float* __restrict__ bb, float* __restrict__ ob)
{
    __shared__ float At[64][36];
    __shared__ float Wt[32][36];
    int y = blockIdx.y;
    const float* W; const float* bias; float* Out; int n0;
    if (y < 12) { W = wf; bias = bf; Out = of; n0 = y * 32; }
    else        { W = wb; bias = bb; Out = ob; n0 = (y - 12) * 32; }
    int row0 = blockIdx.x * 64;
    int tid = threadIdx.x;
    int tx = tid & 15, ty = tid >> 4;
    float acc[4][2] = {};
    for (int k0 = 0; k0 < 256; k0 += 32) {
        #pragma unroll
        for (int i = 0; i < 8; ++i) {
            int idx = tid + i * 256; int rr = idx >> 5, kk = idx & 31;
            At[rr][kk] = A[(size_t)(row0 + rr) * 256 + k0 + kk];
        }
        #pragma unroll
        for (int i = 0; i < 4; ++i) {
            int idx = tid + i * 256; int nn = idx >> 5, kk = idx & 31;
            Wt[nn][kk] = W[(size_t)(n0 + nn) * 256 + k0 + kk];
        }
        __syncthreads();
        #pragma unroll
        for (int kk = 0; kk < 32; kk += 4) {
            float4 w0 = *(const float4*)&Wt[tx][kk];
            float4 w1 = *(const float4*)&Wt[tx + 16][kk];
            #pragma unroll
            for (int rr = 0; rr < 4; ++rr) {
                float4 av = *(const float4*)&At[ty * 4 + rr][kk];
                acc[rr][0] += dot4(av, w0);
                acc[rr][1] += dot4(av, w1);
            }
        }
        __syncthreads();
    }
    #pragma unroll
    for (int cc = 0; cc < 2; ++cc) {
        int n = n0 + tx + cc * 16;
        float badd = bias[n];
        #pragma unroll
        for (int rr = 0; rr < 4; ++rr) {
            int row = row0 + ty * 4 + rr;
            Out[(size_t)row * 384 + n] = acc[rr][cc] + badd;
        }
    }
}

// ---------------------------------------------------------------------------
// Fused dispatch: blocks 0-31 = GRU via MFMA (AGPR B-frags, one LDS-only
// barrier/step — no vmcnt drain); blocks 32-415 = gie; 416-671 = swe.
// ---------------------------------------------------------------------------
struct __align__(16) SmGru { _Float16 hb[2][128]; };
struct __align__(16) SmGemm { float At[64][36]; float Wt[32][36]; };
union __align__(16) SmU { SmGru g; SmGemm m; };

__device__ __forceinline__ void gemm_tile512(
    const float* __restrict__ A, int K, const float* __restrict__ W, int ldw,
    const float* __restrict__ bias, float* __restrict__ Out, int ldout, int N,
    int row0, int n0, SmGemm& sm)
{
    int tid = threadIdx.x;
    int tx = tid & 31, ty = tid >> 5;
    float acc[4] = {};
    for (int k0 = 0; k0 < K; k0 += 32) {
        #pragma unroll
        for (int i = 0; i < 4; ++i) {
            int idx = tid + i * 512; int rr = idx >> 5, kk = idx & 31;
            sm.At[rr][kk] = A[(size_t)(row0 + rr) * K + k0 + kk];
        }
        #pragma unroll
        for (int i = 0; i < 2; ++i) {
            int idx = tid + i * 512; int nn = idx >> 5, kk = idx & 31;
            sm.Wt[nn][kk] = (n0 + nn < N) ? W[(size_t)(n0 + nn) * ldw + k0 + kk] : 0.f;
        }
        __syncthreads();
        #pragma unroll
        for (int kk = 0; kk < 32; kk += 4) {
            float4 w0 = *(const float4*)&sm.Wt[tx][kk];
            #pragma unroll
            for (int rr = 0; rr < 4; ++rr) {
                float4 av = *(const float4*)&sm.At[ty * 4 + rr][kk];
                acc[rr] += dot4(av, w0);
            }
        }
        __syncthreads();
    }
    int n = n0 + tx;
    if (n < N) {
        float badd = bias ? bias[n] : 0.f;
        #pragma unroll
        for (int rr = 0; rr < 4; ++rr)
            Out[(size_t)(row0 + ty * 4 + rr) * ldout + n] = acc[rr] + badd;
    }
}

__global__ __launch_bounds__(512, 2) void gru_fused(
    const float* __restrict__ gi_f, const float* __restrict__ gi_b,
    const unsigned* __restrict__ pk,
    const float* __restrict__ bhh_f, const float* __restrict__ bhh_b,
    float* __restrict__ s_seq,
    const float* __restrict__ e,
    const float* __restrict__ wih_e, const float* __restrict__ bih_e, float* __restrict__ gie,
    const float* __restrict__ sw1_w, const float* __restrict__ sw1_b, float* __restrict__ swe)
{
    __shared__ SmU sm;
    int bx = blockIdx.x;
    if (bx >= 416) {
        int t = bx - 416;
        gemm_tile512(e, 256, sw1_w, 296, sw1_b, swe, 64, 64, (t & 127) * 64, (t >> 7) * 32, sm.m);
        return;
    }
    if (bx >= 32) {
        int t = bx - 32;
        gemm_tile512(e, 256, wih_e, 512, bih_e, gie, 96, 96, (t & 127) * 64, (t >> 7) * 32, sm.m);
        return;
    }

    // ---------------- GRU (MFMA body) ----------------
    int dir = bx >> 4, b = bx & 15;
    const float* gi  = dir ? gi_b  : gi_f;
    const float* bhh = dir ? bhh_b : bhh_f;
    int tid = threadIdx.x;
    int w = tid >> 6;
    int lane = tid & 63;
    int quad = lane >> 4;
    int c = lane & 15;
    int j = 16 * w + c;

    i4 bf[3][4];
    #pragma unroll
    for (int T = 0; T < 3; ++T)
        #pragma unroll
        for (int kt = 0; kt < 4; ++kt)
            bf[T][kt] = *(const i4*)(pk + (size_t)((((dir * 8 + w) * 3 + T) * 4 + kt) * 64 + lane) * 4);
    #pragma unroll
    for (int T = 0; T < 3; ++T)
        #pragma unroll
        for (int kt = 0; kt < 4; ++kt)
            asm volatile("" : "+a"(bf[T][kt]));

    if (tid < 128) sm.g.hb[0][tid] = (_Float16)0.f;

    float bhr = 0.f, bhz = 0.f, bhn = 0.f;
    float gra = 0.f, gza = 0.f, gna = 0.f;
    float grb = 0.f, gzb = 0.f, gnb = 0.f;
    float hreg = 0.f;
    if (lane < 16) {
        bhr = bhh[j]; bhz = bhh[128 + j]; bhn = bhh[256 + j];
        int t0 = dir ? 511 : 0;
        int t1 = dir ? 510 : 1;
        size_t p0 = (size_t)(b * TT + t0) * 384;
        size_t p1 = (size_t)(b * TT + t1) * 384;
        gra = gi[p0 + j]; gza = gi[p0 + 128 + j]; gna = gi[p0 + 256 + j];
        grb = gi[p1 + j]; gzb = gi[p1 + 128 + j]; gnb = gi[p1 + 256 + j];
    }
    __syncthreads();

    int cur = 0;
    auto body = [&](int step, float& gr, float& gz, float& gn) {
        i4 af[4];
        #pragma unroll
        for (int kt = 0; kt < 4; ++kt)
            af[kt] = *(const i4*)(&sm.g.hb[cur][kt * 32 + quad * 8]);
        f4 accr = {0.f, 0.f, 0.f, 0.f};
        f4 accz = {0.f, 0.f, 0.f, 0.f};
        f4 accn = {0.f, 0.f, 0.f, 0.f};
        asm volatile("s_nop 3");
        #pragma unroll
        for (int kt = 0; kt < 4; ++kt) {
            asm volatile("v_mfma_f32_16x16x32_f16 %0, %1, %2, %0" : "+v"(accr) : "v"(af[kt]), "a"(bf[0][kt]));
            asm volatile("v_mfma_f32_16x16x32_f16 %0, %1, %2, %0" : "+v"(accz) : "v"(af[kt]), "a"(bf[1][kt]));
            asm volatile("v_mfma_f32_16x16x32_f16 %0, %1, %2, %0" : "+v"(accn) : "v"(af[kt]), "a"(bf[2][kt]));
        }
        asm volatile("s_nop 7\n\ts_nop 7");
        if (lane < 16) {
            int t = dir ? (511 - step) : step;
            int p = b * TT + t;
            float r = sigmoid_(gr + bhr + accr[0]);
            float z = sigmoid_(gz + bhz + accz[0]);
            float n = tanh_(gn + r * (bhn + accn[0]));
            float hn = (1.f - z) * n + z * hreg;
            hreg = hn;
            sm.g.hb[cur ^ 1][j] = (_Float16)hn;
            s_seq[(size_t)p * 256 + dir * 128 + j] = hn;
            int s2 = step + 2;
            int tp = (s2 < 512) ? (dir ? (511 - s2) : s2) : t;
            size_t p2 = (size_t)(b * TT + tp) * 384;
            gr = gi[p2 + j]; gz = gi[p2 + 128 + j]; gn = gi[p2 + 256 + j];
        }
        lds_barrier();
        cur ^= 1;
    };

    for (int step = 0; step < 512; step += 2) {
        body(step,     gra, gza, gna);
        body(step + 1, grb, gzb, gnb);
    }
}

// ---------------------------------------------------------------------------
// Fused post-scan heads: mu (8), lv (8), sw1 h-part (64, accumulate).
// ---------------------------------------------------------------------------
__global__ __launch_bounds__(256) void heads_k(
    const float* __restrict__ h_seq,
    const float* __restrict__ mu_w, const float* __restrict__ mu_b,
    const float* __restrict__ lv_w, const float* __restrict__ lv_b,
    const float* __restrict__ sw1_w,
    float* __restrict__ out_mu, float* __restrict__ out_lv, float* __restrict__ swe)
{
    __shared__ __align__(16) float Ah[64][32];
    int row0 = blockIdx.x * 64;
    int tid = threadIdx.x;
    #pragma unroll
    for (int i = 0; i < 8; ++i) {
        int idx = tid + i * 256; int rr = idx >> 5, kk = idx & 31;
        Ah[rr][kk] = h_seq[(size_t)(row0 + rr) * 32 + kk];
    }
    __syncthreads();
    int r = tid >> 2, g = tid & 3;
    const float4* av = (const float4*)Ah[r];
    float4 a[8];
    #pragma unroll
    for (int i = 0; i < 8; ++i) a[i] = av[i];
    int row = row0 + r;
    for (int c = 0; c < 20; ++c) {
        int n = g * 20 + c;
        const float* wrow;
        if (n < 8)       wrow = mu_w + n * 32;
        else if (n < 16) wrow = lv_w + (n - 8) * 32;
        else             wrow = sw1_w + (size_t)(n - 16) * 296 + 256;
        const float4* wv = (const float4*)wrow;
        float acc = 0.f;
        #pragma unroll
        for (int i = 0; i < 8; ++i) acc += dot4(wv[i], a[i]);
        if (n < 8)       out_mu[row * 8 + n] = acc + mu_b[n];
        else if (n < 16) out_lv[row * 8 + (n - 8)] = acc + lv_b[n - 8];
        else             swe[(size_t)row * 64 + (n - 16)] += acc;
    }
}

// ---------------------------------------------------------------------------
// Controller h-scan. 16 WGs, 128 threads. Single LDS-only barrier/step.
// ---------------------------------------------------------------------------
__global__ __launch_bounds__(128, 1) void ctrl_h_scan(
    const float* __restrict__ gie, const unsigned* __restrict__ pk_e,
    const float* __restrict__ bhh_e, float* __restrict__ h_seq)
{
    int b = blockIdx.x, tid = threadIdx.x;
    int k = tid >> 2;
    int s = tid & 3;

    unsigned ag[12];
    {
        const uint4* wp = (const uint4*)(pk_e + ((size_t)(s * 32) + k) * 12);
        #pragma unroll
        for (int i = 0; i < 3; ++i) {
            uint4 u = wp[i];
            AGPR_STORE(ag[4 * i + 0], u.x);
            AGPR_STORE(ag[4 * i + 1], u.y);
            AGPR_STORE(ag[4 * i + 2], u.z);
            AGPR_STORE(ag[4 * i + 3], u.w);
        }
    }

    __shared__ __align__(16) _Float16 hb[2][32];
    if (tid < 32) hb[0][tid] = (_Float16)0.f;

    int pbase = b * TT;
    float bhr = 0.f, bhz = 0.f, bhn = 0.f;
    float g1a = 0.f, g2a = 0.f, g3a = 0.f, g1b = 0.f, g2b = 0.f, g3b = 0.f;
    float hreg = 0.f;
    if (s == 0) {
        bhr = bhh_e[k]; bhz = bhh_e[32 + k]; bhn = bhh_e[64 + k];
        size_t p0 = (size_t)pbase * 96, p1 = (size_t)(pbase + 1) * 96;
        g1a = gie[p0 + k]; g2a = gie[p0 + 32 + k]; g3a = gie[p0 + 64 + k];
        g1b = gie[p1 + k]; g2b = gie[p1 + 32 + k]; g3b = gie[p1 + 64 + k];
    }
    __syncthreads();

    int cur = 0;
    auto body = [&](int t, float& g1, float& g2, float& g3) {
        const uint4* hv = (const uint4*)(&hb[cur][0]) + s;
        uint4 h4 = hv[0];
        unsigned hw[4] = { h4.x, h4.y, h4.z, h4.w };
        float a0 = 0.f, a1 = 0.f, a2 = 0.f;
        #pragma unroll
        for (int m = 0; m < 4; ++m) {
            unsigned w0, w1, w2;
            AGPR_LOAD(w0, ag[m]);
            AGPR_LOAD(w1, ag[4 + m]);
            AGPR_LOAD(w2, ag[8 + m]);
            h2v hh = u2h2(hw[m]);
            a0 = __builtin_amdgcn_fdot2(u2h2(w0), hh, a0, false);
            a1 = __builtin_amdgcn_fdot2(u2h2(w1), hh, a1, false);
            a2 = __builtin_amdgcn_fdot2(u2h2(w2), hh, a2, false);
        }
        a0 = quad_sum(a0);
        a1 = quad_sum(a1);
        a2 = quad_sum(a2);

        if (s == 0) {
            float r = sigmoid_(g1 + bhr + a0);
            float z = sigmoid_(g2 + bhz + a1);
            float n = tanh_(g3 + r * (bhn + a2));
            float hn = (1.f - z) * n + z * hreg;
            hreg = hn;
            hb[cur ^ 1][k] = (_Float16)hn;
            h_seq[(size_t)(pbase + t) * 32 + k] = hn;
            int t2 = (t + 2 < 512) ? t + 2 : t;
            size_t p2 = (size_t)(pbase + t2) * 96;
            g1 = gie[p2 + k]; g2 = gie[p2 + 32 + k]; g3 = gie[p2 + 64 + k];
        }
        lds_barrier();
        cur ^= 1;
    };

    for (int t = 0; t < 512; t += 2) {
        body(t,     g1a, g2a, g3a);
        body(t + 1, g1b, g2b, g3b);
    }
}

// ---------------------------------------------------------------------------
// Controller z/beta scan. 16 WGs, 1 wave, no LDS, no barriers, DPP reduce.
// ---------------------------------------------------------------------------
__global__ __launch_bounds__(64, 1) void ctrl_z_scan(
    const float* __restrict__ hid_pre, const float* __restrict__ sw1_w,
    const float* __restrict__ sw2_w, const float* __restrict__ sw2_b,
    const float* __restrict__ eps, const float* __restrict__ mu_o,
    const float* __restrict__ lv_o, float* __restrict__ beta_o, float* __restrict__ z_o)
{
    int b = blockIdx.x, q = threadIdx.x;
    float wz[8];
    #pragma unroll
    for (int x = 0; x < 8; ++x) wz[x] = sw1_w[(size_t)q * 296 + 288 + x];
    float w2 = sw2_w[q];
    float bb = sw2_b[0];
    float4 z03 = {0.f, 0.f, 0.f, 0.f}, z47 = {0.f, 0.f, 0.f, 0.f};
    int pbase = b * TT;

    auto loadcand = [&](int p, float4& c03, float4& c47) {
        float4 m0 = *(const float4*)(mu_o + p * 8);
        float4 m1 = *(const float4*)(mu_o + p * 8 + 4);
        float4 l0 = *(const float4*)(lv_o + p * 8);
        float4 l1 = *(const float4*)(lv_o + p * 8 + 4);
        float4 e0 = *(const float4*)(eps + p * 8);
        float4 e1 = *(const float4*)(eps + p * 8 + 4);
        c03 = make_float4(m0.x + __expf(0.5f * l0.x) * e0.x, m0.y + __expf(0.5f * l0.y) * e0.y,
                          m0.z + __expf(0.5f * l0.z) * e0.z, m0.w + __expf(0.5f * l0.w) * e0.w);
        c47 = make_float4(m1.x + __expf(0.5f * l1.x) * e1.x, m1.y + __expf(0.5f * l1.y) * e1.y,
                          m1.z + __expf(0.5f * l1.z) * e1.z, m1.w + __expf(0.5f * l1.w) * e1.w);
    };

    float hpa = hid_pre[(size_t)pbase * 64 + q];
    float hpb = hid_pre[(size_t)(pbase + 1) * 64 + q];
    float4 c03a, c47a, c03b, c47b;
    loadcand(pbase, c03a, c47a);
    loadcand(pbase + 1, c03b, c47b);

    auto body = [&](int t, float& hp, float4& c03, float4& c47) {
        int p = pbase + t;
        float a = hp
            + wz[0] * z03.x + wz[1] * z03.y + wz[2] * z03.z + wz[3] * z03.w
            + wz[4] * z47.x + wz[5] * z47.y + wz[6] * z47.z + wz[7] * z47.w;
        float hid = tanh_(a);
        float total = wave_sum_bcast(w2 * hid);
        float beta = sigmoid_(total + bb);
        float omb = 1.f - beta;
        z03.x = beta * c03.x + omb * z03.x;  z03.y = beta * c03.y + omb * z03.y;
        z03.z = beta * c03.z + omb * z03.z;  z03.w = beta * c03.w + omb * z03.w;
        z47.x = beta * c47.x + omb * z47.x;  z47.y = beta * c47.y + omb * z47.y;
        z47.z = beta * c47.z + omb * z47.z;  z47.w = beta * c47.w + omb * z47.w;
        if (q == 0) {
            *(float4*)(z_o + p * 8) = z03;
            *(float4*)(z_o + p * 8 + 4) = z47;
            beta_o[p] = beta;
        }
        int t2 = (t + 2 < 512) ? t + 2 : t;
        hp = hid_pre[(size_t)(pbase + t2) * 64 + q];
        loadcand(pbase + t2, c03, c47);
    };

    for (int t = 0; t < 512; t += 2) {
        body(t,     hpa, c03a, c47a);
        body(t + 1, hpb, c03b, c47b);
    }
}

// ---------------------------------------------------------------------------
// Decoder hypernet + rank-R perturbation + LayerNorm + head. P=8/WG.
// ---------------------------------------------------------------------------
__global__ __launch_bounds__(256, 3) void decoder_final(
    const float* __restrict__ e_seq, const float* __restrict__ z_o,
    const float* __restrict__ dec1_w, const float* __restrict__ dec1_b,
    const float* __restrict__ dec2_w, const float* __restrict__ dec2_b,
    const float* __restrict__ ln_g, const float* __restrict__ ln_b,
    const float* __restrict__ head_w, const float* __restrict__ head_b,
    float* __restrict__ logits)
{
    __shared__ __align__(16) float e_l[8][256];
    __shared__ __align__(16) float hmid[8][32];
    __shared__ float zl[8][8];
    __shared__ float tmpw[8][16];
    __shared__ __align__(16) float partb[2048];
    __shared__ float red1[8][16];
    __shared__ float red2[8][16];
    __shared__ float stats[8][2];
    int tid = threadIdx.x;
    int p0 = blockIdx.x * 8;

    {
        const float4* eg = (const float4*)(e_seq + (size_t)p0 * 256);
        float4* el4 = (float4*)&e_l[0][0];
        el4[tid] = eg[tid];
        el4[tid + 256] = eg[tid + 256];
        if (tid < 64) ((float*)zl)[tid] = z_o[p0 * 8 + tid];
    }
    __syncthreads();
    {
        int pp = tid >> 5, g = tid & 31;
        float a = dec1_b[g];
        #pragma unroll
        for (int x = 0; x < 8; ++x) a += dec1_w[g * 8 + x] * zl[pp][x];
        hmid[pp][g] = tanh_(a);
    }
    __syncthreads();
    // ---- pass B: tmp[pp][r] = sum_d Bm[d,r]*e[d]
    {
        int r = tid & 15, dgrp = tid >> 4;
        float acc[8];
        #pragma unroll
        for (int pp = 0; pp < 8; ++pp) acc[pp] = 0.f;
        for (int iblk = 0; iblk < 8; ++iblk) {
            float4 wr[2][8]; float wb[2]; int dd[2];
            #pragma unroll
            for (int ii = 0; ii < 2; ++ii) {
                int d = dgrp + 16 * (iblk * 2 + ii);
                dd[ii] = d;
                int row = 4096 + d * 16 + r;
                const float4* wp = (const float4*)(dec2_w + (size_t)row * 32);
                #pragma unroll
                for (int g = 0; g < 8; ++g) wr[ii][g] = wp[g];
                wb[ii] = dec2_b[row];
            }
            #pragma unroll 1
            for (int pp = 0; pp < 8; ++pp) {
                const float4* hv = (const float4*)hmid[pp];
                float b0 = wb[0], b1 = wb[1];
                #pragma unroll
                for (int g = 0; g < 8; ++g) {
                    float4 hh = hv[g];
                    b0 += dot4(wr[0][g], hh);
                    b1 += dot4(wr[1][g], hh);
                }
                acc[pp] += b0 * e_l[pp][dd[0]] + b1 * e_l[pp][dd[1]];
            }
        }
        #pragma unroll
        for (int pp = 0; pp < 8; ++pp) partb[(pp * 16 + r) * 16 + dgrp] = acc[pp];
    }
    __syncthreads();
    if (tid < 128) {
        int pp = tid >> 4, rr = tid & 15;
        float s = 0.f;
        #pragma unroll
        for (int dg = 0; dg < 16; ++dg) s += partb[(pp * 16 + rr) * 16 + dg];
        tmpw[pp][rr] = s;
    }
    __syncthreads();
    // ---- pass A
    {
        int d = tid;
        float po[8];
        #pragma unroll
        for (int pp = 0; pp < 8; ++pp) po[pp] = e_l[pp][d];
        for (int rblk = 0; rblk < 8; ++rblk) {
            float4 wr[2][8]; float wb[2];
            #pragma unroll
            for (int ii = 0; ii < 2; ++ii) {
                int row = d * 16 + rblk * 2 + ii;
                const float4* wp = (const float4*)(dec2_w + (size_t)row * 32);
                #pragma unroll
                for (int g = 0; g < 8; ++g) wr[ii][g] = wp[g];
                wb[ii] = dec2_b[row];
            }
            #pragma unroll 1
            for (int pp = 0; pp < 8; ++pp) {
                const float4* hv = (const float4*)hmid[pp];
                float a0 = wb[0], a1 = wb[1];
                #pragma unroll
                for (int g = 0; g < 8; ++g) {
                    float4 hh = hv[g];
                    a0 += dot4(wr[0][g], hh);
                    a1 += dot4(wr[1][g], hh);
                }
                po[pp] += a0 * tmpw[pp][rblk * 2] + a1 * tmpw[pp][rblk * 2 + 1];
            }
        }
        #pragma unroll
        for (int pp = 0; pp < 8; ++pp) partb[pp * 256 + d] = po[pp];
    }
    __syncthreads();
    if (tid < 128) {
        int pp = tid >> 4, c = tid & 15;
        float s = 0.f, s2 = 0.f;
        #pragma unroll
        for (int i = 0; i < 16; ++i) { float v = partb[pp * 256 + c * 16 + i]; s += v; s2 += v * v; }
        red1[pp][c] = s; red2[pp][c] = s2;
    }
    __syncthreads();
    if (tid < 8) {
        float s = 0.f, s2 = 0.f;
        #pragma unroll
        for (int c = 0; c < 16; ++c) { s += red1[tid][c]; s2 += red2[tid][c]; }
        float mean = s * (1.f / 256.f);
        float var = s2 * (1.f / 256.f) - mean * mean;
        stats[tid][0] = mean;
        stats[tid][1] = rsqrtf(var + 1e-5f);
    }
    __syncthreads();
    {
        int d = tid;
        float g = ln_g[d], bln = ln_b[d];
        #pragma unroll
        for (int pp = 0; pp < 8; ++pp) {
            float v = (partb[pp * 256 + d] - stats[pp][0]) * stats[pp][1];
            partb[pp * 256 + d] = v * g + bln;
        }
    }
    __syncthreads();
    if (tid < 144) {
        int pp = tid / 18, na = tid - pp * 18;
        float a = head_b[na];
        for (int d2 = 0; d2 < 256; ++d2)
            a += partb[pp * 256 + d2] * head_w[na * 256 + d2];
        logits[(size_t)(p0 + pp) * 18 + na] = a;
    }
}

// ---------------------------------------------------------------------------
extern "C" void kernel_launch(void* const* d_in, const int* in_sizes, int n_in,
                              void* d_out, int out_size, void* d_ws, size_t ws_size,
                              hipStream_t stream) {
    (void)in_sizes; (void)n_in; (void)out_size; (void)ws_size;
    const float* e     = (const float*)d_in[0];
    const float* eps   = (const float*)d_in[1];
    const float* wih_f = (const float*)d_in[2];
    const float* whh_f = (const float*)d_in[3];
    const float* bih_f = (const float*)d_in[4];
    const float* bhh_f = (const float*)d_in[5];
    const float* wih_b = (const float*)d_in[6];
    const float* whh_b = (const float*)d_in[7];
    const float* bih_b = (const float*)d_in[8];
    const float* bhh_b = (const float*)d_in[9];
    const float* wih_e = (const float*)d_in[10];
    const float* whh_e = (const float*)d_in[11];
    const float* bih_e = (const float*)d_in[12];
    const float* bhh_e = (const float*)d_in[13];
    const float* mu_w  = (const float*)d_in[14];
    const float* mu_b  = (const float*)d_in[15];
    const float* lv_w  = (const float*)d_in[16];
    const float* lv_b  = (const float*)d_in[17];
    const float* sw1_w = (const float*)d_in[18];
    const float* sw1_b = (const float*)d_in[19];
    const float* sw2_w = (const float*)d_in[20];
    const float* sw2_b = (const float*)d_in[21];
    const float* dec1_w = (const float*)d_in[22];
    const float* dec1_b = (const float*)d_in[23];
    const float* dec2_w = (const float*)d_in[24];
    const float* dec2_b = (const float*)d_in[25];
    const float* ln_g  = (const float*)d_in[26];
    const float* ln_b  = (const float*)d_in[27];
    const float* head_w = (const float*)d_in[28];
    const float* head_b = (const float*)d_in[29];

    float* ws    = (float*)d_ws;
    float* gi_f  = ws;                       // 8192*384
    float* gi_b  = gi_f + 3145728;           // 8192*384
    float* gie   = gi_b + 3145728;           // 8192*96
    float* swe   = gie + 786432;             // 8192*64 (hid_pre)
    float* s_seq = swe + 524288;             // 8192*256
    float* h_seq = s_seq + 2097152;          // 8192*32
    unsigned* pk   = (unsigned*)(h_seq + 262144);  // 49152 dwords (gru f16 B-frags)
    unsigned* pk_e = pk + 49152;                   // 1536 dwords (ctrl f16 pairs)

    float* out       = (float*)d_out;
    float* out_logit = out;                  // 147456
    float* out_mu    = out + 147456;         // 65536
    float* out_lv    = out + 212992;         // 65536
    float* out_beta  = out + 278528;         // 8192
    float* out_z     = out + 286720;         // 65536

    // pack recurrent weights to f16 (thread/frag-contiguous layouts)
    pack_w<<<198, 256, 0, stream>>>(whh_f, whh_b, whh_e, pk, pk_e);
    // both big input projections in one launch
    gemm_gi<<<dim3(128, 24), 256, 0, stream>>>(e, wih_f, bih_f, gi_f, wih_b, bih_b, gi_b);
    // GRU recurrence (MFMA) fused with the independent gie/swe e-projections
    gru_fused<<<672, 512, 0, stream>>>(gi_f, gi_b, pk, bhh_f, bhh_b, s_seq,
                                       e, wih_e, bih_e, gie, sw1_w, sw1_b, swe);
    // add s-part of controller GRU input projection
    gemm_k<<<dim3(128, 3), 256, 0, stream>>>(s_seq, 256, wih_e + 256, 512, nullptr, gie, 96, 96, 1);
    // controller h scan
    ctrl_h_scan<<<16, 128, 0, stream>>>(gie, pk_e, bhh_e, h_seq);
    // fused mu / logvar / switching-unit h-part
    heads_k<<<128, 256, 0, stream>>>(h_seq, mu_w, mu_b, lv_w, lv_b, sw1_w, out_mu, out_lv, swe);
    // beta / z scan
    ctrl_z_scan<<<16, 64, 0, stream>>>(swe, sw1_w, sw2_w, sw2_b, eps, out_mu, out_lv, out_beta, out_z);
    // decoder hypernet + perturbation + LN + head
    decoder_final<<<1024, 256, 0, stream>>>(e, out_z, dec1_w, dec1_b, dec2_w, dec2_b,
                                            ln_g, ln_b, head_w, head_b, out_logit);
}